// Round 5
// baseline (894.332 us; speedup 1.0000x reference)
//
#include <hip/hip_runtime.h>
#include <hip/hip_bf16.h>

// WordSentAtt: qf = relu(Q@W^T + b); S = qf@K^T (masked); attn = softmax; O = attn@K
// B=32, Lq=Lk=D=1024, f32 in/out. Split-bf16 (hi/lo) MFMA for qf and S.
// R5: (1) qf intermediate stored in MFMA A-FRAGMENT order (hi|lo, 64MB each,
//     fills d_out) so attn2 q-frag loads are lane-contiguous (R4's scattered
//     4KB-stride loads killed it). (2) attn2 BK=128: 64 segments x 48 MFMA
//     (was 128 x 24), K dbuf 128KB LDS. (3) attn bf16 output -> ws Qhi region
//     (dead after qf2); pv2 merged to one launch grid(8,32,2) writing d_out.

typedef __attribute__((ext_vector_type(4))) float f32x4;
typedef __attribute__((ext_vector_type(8))) short s16x8;

#define MFMA16(a, b, c) __builtin_amdgcn_mfma_f32_16x16x32_bf16((a), (b), (c), 0, 0, 0)

__device__ __forceinline__ unsigned short f2bf(float x) {
  unsigned u = __builtin_bit_cast(unsigned, x);
  return (unsigned short)((u + 0x7FFFu + ((u >> 16) & 1u)) >> 16);
}
__device__ __forceinline__ float bf2f(unsigned short h) {
  return __builtin_bit_cast(float, ((unsigned)h) << 16);
}
__device__ __forceinline__ int swz(int row, int col) {
  return (row * 64 + col) ^ ((row & 7) << 3);
}
__device__ __forceinline__ void cvt8(const float* __restrict__ s, s16x8& h8, s16x8& l8) {
  f32x4 a = *(const f32x4*)s;
  f32x4 b = *(const f32x4*)(s + 4);
#pragma unroll
  for (int i = 0; i < 8; i++) {
    float v = (i < 4) ? a[i] : b[i - 4];
    unsigned short hu = f2bf(v);
    unsigned short lu = f2bf(v - bf2f(hu));
    h8[i] = (short)hu;
    l8[i] = (short)lu;
  }
}
__device__ __forceinline__ void gld16(const void* g, void* lds) {
  __builtin_amdgcn_global_load_lds((const __attribute__((address_space(1))) unsigned int*)g,
                                   (__attribute__((address_space(3))) unsigned int*)lds, 16, 0, 0);
}

// ws layout (bytes)
#define OFF_KHI 0ULL
#define OFF_KLO 67108864ULL
#define OFF_KHIT 134217728ULL
#define OFF_QHI 201326592ULL  // qf2 inputs Qhi/Qlo; attn bf16 reuses QHI after qf2
#define OFF_QLO 268435456ULL
#define OFF_WHI 335544320ULL
#define OFF_WLO 337641472ULL
#define WS_TIER_A 339738624ULL
#define QA_LO 33554432ULL  // u16 offset of lo plane inside d_out frag layout

// ================= pre-convert kernels =================
__global__ __launch_bounds__(256) void k_cvt_pair(const float* __restrict__ src,
                                                  unsigned short* __restrict__ hi,
                                                  unsigned short* __restrict__ lo, int n8) {
  int i = blockIdx.x * 256 + threadIdx.x;
  if (i >= n8) return;
  s16x8 h, l;
  cvt8(src + (size_t)i * 8, h, l);
  *(s16x8*)(hi + (size_t)i * 8) = h;
  *(s16x8*)(lo + (size_t)i * 8) = l;
}

__global__ __launch_bounds__(256) void k_cvt_k(const float* __restrict__ K,
                                               unsigned short* __restrict__ Khi,
                                               unsigned short* __restrict__ Klo,
                                               unsigned short* __restrict__ KhiT) {
  __shared__ unsigned T[64 * 65];
  const int t = threadIdx.x;
  const int db0 = blockIdx.x * 64, kb0 = blockIdx.y * 64, b = blockIdx.z;
  const size_t base = (size_t)b * 1024 * 1024;
#pragma unroll
  for (int i = 0; i < 2; i++) {
    const int r = (t >> 3) + i * 32, c0 = (t & 7) * 8;
    s16x8 h, l;
    cvt8(K + base + (size_t)(kb0 + r) * 1024 + db0 + c0, h, l);
    *(s16x8*)(Khi + base + (size_t)(kb0 + r) * 1024 + db0 + c0) = h;
    *(s16x8*)(Klo + base + (size_t)(kb0 + r) * 1024 + db0 + c0) = l;
#pragma unroll
    for (int j = 0; j < 8; j++)
      T[r * 65 + c0 + j] = ((unsigned)(unsigned short)h[j] << 16) | (unsigned short)l[j];
  }
  __syncthreads();
#pragma unroll
  for (int i = 0; i < 2; i++) {
    const int rd = (t >> 3) + i * 32, ck0 = (t & 7) * 8;
    s16x8 h;
#pragma unroll
    for (int j = 0; j < 8; j++) h[j] = (short)(unsigned short)(T[(ck0 + j) * 65 + rd] >> 16);
    *(s16x8*)(KhiT + base + (size_t)(db0 + rd) * 1024 + kb0 + ck0) = h;
  }
}

// ================= qf GEMM -> fragment-ordered output =================
// grid (256,8), 256 thr = 4 waves (2x2). 128x128 tile, BK=64.
// Output layout (u16, in d_out): hi[qblk][kchunk32][lane64][8], lo at +QA_LO.
//   element (R,c): qblk=R>>4, kchunk=c>>5, lane=(R&15)+16*((c>>3)&3), j=c&7.
__global__ __launch_bounds__(256, 2) void k_qf2(const unsigned short* __restrict__ Qhi,
                                                const unsigned short* __restrict__ Qlo,
                                                const unsigned short* __restrict__ Whi,
                                                const unsigned short* __restrict__ Wlo,
                                                const float* __restrict__ bias,
                                                float* __restrict__ outp) {
  __shared__ __align__(16) unsigned short Ah[128 * 64], Al[128 * 64], Bh[128 * 64], Bl[128 * 64];
  const int t = threadIdx.x;
  const int i = blockIdx.x + blockIdx.y * 256;
  const int x = i & 7, j = i >> 3;
  const int n0 = (j & 7) * 128;
  const int m0 = (x * 32 + (j >> 3)) * 128;
  const int w = t >> 6, l = t & 63, wm = w >> 1, wn = w & 1, g = l >> 4, ln = l & 15;
  const int lrow = l >> 3, lc8 = (l & 7) * 8;
  const f32x4 fz = {0.f, 0.f, 0.f, 0.f};
  f32x4 acc[4][4];
#pragma unroll
  for (int a = 0; a < 4; a++)
#pragma unroll
    for (int bq = 0; bq < 4; bq++) acc[a][bq] = fz;
#pragma unroll 1
  for (int k0 = 0; k0 < 1024; k0 += 64) {
#pragma unroll
    for (int jj = 0; jj < 4; jj++) {
      const int ch = w * 4 + jj;
      const int row = ch * 8 + lrow;
      const int sc = lc8 ^ (lrow << 3);
      gld16(Qhi + (size_t)(m0 + row) * 1024 + k0 + sc, &Ah[ch * 512]);
      gld16(Qlo + (size_t)(m0 + row) * 1024 + k0 + sc, &Al[ch * 512]);
      gld16(Whi + (size_t)(n0 + row) * 1024 + k0 + sc, &Bh[ch * 512]);
      gld16(Wlo + (size_t)(n0 + row) * 1024 + k0 + sc, &Bl[ch * 512]);
    }
    __syncthreads();
#pragma unroll
    for (int ks = 0; ks < 2; ks++) {
      const int kc = ks * 32 + g * 8;
      s16x8 ah[4], al[4], bh[4], bl[4];
#pragma unroll
      for (int mf = 0; mf < 4; mf++) {
        const int row = wm * 64 + mf * 16 + ln;
        const int idx = row * 64 + (kc ^ ((row & 7) << 3));
        ah[mf] = *(const s16x8*)&Ah[idx];
        al[mf] = *(const s16x8*)&Al[idx];
      }
#pragma unroll
      for (int nf = 0; nf < 4; nf++) {
        const int row = wn * 64 + nf * 16 + ln;
        const int idx = row * 64 + (kc ^ ((row & 7) << 3));
        bh[nf] = *(const s16x8*)&Bh[idx];
        bl[nf] = *(const s16x8*)&Bl[idx];
      }
#pragma unroll
      for (int mf = 0; mf < 4; mf++)
#pragma unroll
        for (int nf = 0; nf < 4; nf++) {
          acc[mf][nf] = MFMA16(ah[mf], bh[nf], acc[mf][nf]);
          acc[mf][nf] = MFMA16(ah[mf], bl[nf], acc[mf][nf]);
          acc[mf][nf] = MFMA16(al[mf], bh[nf], acc[mf][nf]);
        }
    }
    __syncthreads();
  }
  unsigned short* qA = (unsigned short*)outp;
#pragma unroll
  for (int nf = 0; nf < 4; nf++) {
    const int c = n0 + wn * 64 + nf * 16 + ln;
    const float bv = bias[c];
    const int kchunk = c >> 5, lhib = ((c >> 3) & 3) << 4, jj = c & 7;
#pragma unroll
    for (int mf = 0; mf < 4; mf++)
#pragma unroll
      for (int r = 0; r < 4; r++) {
        const int R = m0 + wm * 64 + mf * 16 + g * 4 + r;
        float v = acc[mf][nf][r] + bv;
        v = v > 0.f ? v : 0.f;
        unsigned short h = f2bf(v);
        const size_t fo = (((size_t)(R >> 4) * 32 + kchunk) * 64 + ((R & 15) + lhib)) * 8 + jj;
        qA[fo] = h;
        qA[QA_LO + fo] = f2bf(v - bf2f(h));
      }
  }
}

// ================= score GEMM + masked softmax (R5: BK=128, frag-q) ==========
// grid (16,32), 512 thr = 8 waves (2 wm x 4 wn). S[64][1024] in regs.
// 64 segments (8 dc x 8 kt) x 48 MFMA/wave; K dbuf 128KB; q coalesced frag loads.
__global__ __launch_bounds__(512, 1) void k_attn2(const unsigned short* __restrict__ Khi,
                                                  const unsigned short* __restrict__ Klo,
                                                  const float* __restrict__ mask,
                                                  const unsigned short* __restrict__ qA,
                                                  unsigned short* __restrict__ attnw) {
  __shared__ __align__(16) unsigned short kbuf[2][2][128 * 128];  // [buf][plane]
  __shared__ float mask_s[1024];
  __shared__ float red[4][64];
  const int t = threadIdx.x;
  const int i = blockIdx.y * 16 + blockIdx.x;
  const int x = i & 7, jj = i >> 3;
  const int b = x * 4 + (jj >> 4), qt = jj & 15;
  const int q0 = qt * 64;
  const int w = t >> 6, l = t & 63, wm = w >> 2, wn = w & 3, g = l >> 4, ln = l & 15;
  for (int ii = t; ii < 1024; ii += 512) mask_s[ii] = mask[b * 1024 + ii];
  const f32x4 fz = {0.f, 0.f, 0.f, 0.f};
  f32x4 acc[8][2][2];
#pragma unroll
  for (int kt = 0; kt < 8; kt++)
#pragma unroll
    for (int mf = 0; mf < 2; mf++)
#pragma unroll
      for (int nf = 0; nf < 2; nf++) acc[kt][mf][nf] = fz;
  const size_t kbase = (size_t)b * 1024 * 1024;
  const int qblk0 = (b * 1024 + q0) >> 4;

  // stage one 128(k-rows) x 128(d-cols) K tile (hi+lo) into kbuf[buf]
  auto stageK = [&](int buf, int kt, int dc) {
#pragma unroll
    for (int jj2 = 0; jj2 < 4; jj2++) {
      const int ch = w * 4 + jj2;                  // 0..31 (4 rows each)
      const int row = ch * 4 + (l >> 4);           // 0..127
      const int scc = ((l & 15) ^ (row & 7)) * 8;  // inverse swizzle on source
      const size_t go = kbase + (size_t)(kt * 128 + row) * 1024 + dc * 128 + scc;
      gld16(Khi + go, &kbuf[buf][0][ch * 512]);
      gld16(Klo + go, &kbuf[buf][1][ch * 512]);
    }
  };

  stageK(0, 0, 0);
  __syncthreads();
  int cur = 0;
#pragma unroll 1
  for (int dc = 0; dc < 8; dc++) {
    // q-frags for this 128-col band: coalesced (lane-contiguous) loads
    s16x8 qh[2][4], ql[2][4];
#pragma unroll
    for (int mf = 0; mf < 2; mf++) {
      const int qb = qblk0 + wm * 2 + mf;
#pragma unroll
      for (int ks = 0; ks < 4; ks++) {
        const size_t fo = (((size_t)qb * 32 + dc * 4 + ks) * 64 + l) * 8;
        qh[mf][ks] = *(const s16x8*)(qA + fo);
        ql[mf][ks] = *(const s16x8*)(qA + QA_LO + fo);
      }
    }
#pragma unroll  // full: acc[kt] must be statically indexed (rule #20)
    for (int kt = 0; kt < 8; kt++) {
      if (!(dc == 7 && kt == 7)) {
        const int nkt = (kt + 1) & 7;
        const int ndc = (kt == 7) ? dc + 1 : dc;
        stageK(cur ^ 1, nkt, ndc);
      }
#pragma unroll
      for (int ks = 0; ks < 4; ks++) {
        s16x8 bh[2], bl[2];
#pragma unroll
        for (int nf = 0; nf < 2; nf++) {
          const int row = wn * 32 + nf * 16 + ln;
          const int idx = row * 128 + (((ks * 4 + g) ^ (row & 7)) * 8);
          bh[nf] = *(const s16x8*)&kbuf[cur][0][idx];
          bl[nf] = *(const s16x8*)&kbuf[cur][1][idx];
        }
#pragma unroll
        for (int mf = 0; mf < 2; mf++)
#pragma unroll
          for (int nf = 0; nf < 2; nf++) {
            acc[kt][mf][nf] = MFMA16(qh[mf][ks], bh[nf], acc[kt][mf][nf]);
            acc[kt][mf][nf] = MFMA16(qh[mf][ks], bl[nf], acc[kt][mf][nf]);
            acc[kt][mf][nf] = MFMA16(ql[mf][ks], bh[nf], acc[kt][mf][nf]);
          }
      }
      __syncthreads();
      cur ^= 1;
    }
  }
  // ---- masked softmax ----
  float rmax[2][4];
#pragma unroll
  for (int mf = 0; mf < 2; mf++)
#pragma unroll
    for (int r = 0; r < 4; r++) rmax[mf][r] = -1e30f;
#pragma unroll
  for (int kt = 0; kt < 8; kt++)
#pragma unroll
    for (int nf = 0; nf < 2; nf++) {
      const int k = kt * 128 + wn * 32 + nf * 16 + ln;
      const bool mk = mask_s[k] != 0.f;
#pragma unroll
      for (int mf = 0; mf < 2; mf++)
#pragma unroll
        for (int r = 0; r < 4; r++)
          if (mk) rmax[mf][r] = fmaxf(rmax[mf][r], acc[kt][mf][nf][r]);
    }
#pragma unroll
  for (int off = 1; off < 16; off <<= 1)
#pragma unroll
    for (int mf = 0; mf < 2; mf++)
#pragma unroll
      for (int r = 0; r < 4; r++) rmax[mf][r] = fmaxf(rmax[mf][r], __shfl_xor(rmax[mf][r], off));
  if (ln == 0) {
#pragma unroll
    for (int mf = 0; mf < 2; mf++)
#pragma unroll
      for (int r = 0; r < 4; r++) red[wn][wm * 32 + mf * 16 + g * 4 + r] = rmax[mf][r];
  }
  __syncthreads();
#pragma unroll
  for (int mf = 0; mf < 2; mf++)
#pragma unroll
    for (int r = 0; r < 4; r++) {
      const int row = wm * 32 + mf * 16 + g * 4 + r;
      rmax[mf][r] = fmaxf(fmaxf(red[0][row], red[1][row]), fmaxf(red[2][row], red[3][row]));
    }
  __syncthreads();
  float rsum[2][4];
#pragma unroll
  for (int mf = 0; mf < 2; mf++)
#pragma unroll
    for (int r = 0; r < 4; r++) rsum[mf][r] = 0.f;
#pragma unroll
  for (int kt = 0; kt < 8; kt++)
#pragma unroll
    for (int nf = 0; nf < 2; nf++) {
      const int k = kt * 128 + wn * 32 + nf * 16 + ln;
      const bool mk = mask_s[k] != 0.f;
#pragma unroll
      for (int mf = 0; mf < 2; mf++)
#pragma unroll
        for (int r = 0; r < 4; r++)
          if (mk) rsum[mf][r] += __expf(acc[kt][mf][nf][r] - rmax[mf][r]);
    }
#pragma unroll
  for (int off = 1; off < 16; off <<= 1)
#pragma unroll
    for (int mf = 0; mf < 2; mf++)
#pragma unroll
      for (int r = 0; r < 4; r++) rsum[mf][r] += __shfl_xor(rsum[mf][r], off);
  if (ln == 0) {
#pragma unroll
    for (int mf = 0; mf < 2; mf++)
#pragma unroll
      for (int r = 0; r < 4; r++) red[wn][wm * 32 + mf * 16 + g * 4 + r] = rsum[mf][r];
  }
  __syncthreads();
  float rinv[2][4];
#pragma unroll
  for (int mf = 0; mf < 2; mf++)
#pragma unroll
    for (int r = 0; r < 4; r++) {
      const int row = wm * 32 + mf * 16 + g * 4 + r;
      rinv[mf][r] = 1.f / (red[0][row] + red[1][row] + red[2][row] + red[3][row]);
    }
  // attn bf16 -> ws (row-major [R][k], 2KB rows)
#pragma unroll
  for (int kt = 0; kt < 8; kt++)
#pragma unroll
    for (int nf = 0; nf < 2; nf++) {
      const int k = kt * 128 + wn * 32 + nf * 16 + ln;
      const bool mk = mask_s[k] != 0.f;
#pragma unroll
      for (int mf = 0; mf < 2; mf++)
#pragma unroll
        for (int r = 0; r < 4; r++) {
          const int q = q0 + wm * 32 + mf * 16 + g * 4 + r;
          float p = mk ? __expf(acc[kt][mf][nf][r] - rmax[mf][r]) * rinv[mf][r] : 0.f;
          attnw[(size_t)(b * 1024 + q) * 1024 + k] = f2bf(p);
        }
    }
}

// ================= O = attn @ K via KhiT (single launch, z = d-half) ==========
// grid (8,32,2), 512 thr = 8 waves (2 wm x 4 wd). 128q x 512d, BK=64.
__global__ __launch_bounds__(512, 2) void k_pv2(const unsigned short* __restrict__ KhiT,
                                                const unsigned short* __restrict__ attnw,
                                                float* __restrict__ dout) {
  __shared__ __align__(16) unsigned short P[128 * 64];
  __shared__ __align__(16) unsigned short KT[512 * 64];
  const int t = threadIdx.x;
  const int i = blockIdx.y * 8 + blockIdx.x;
  const int x = i & 7, jj = i >> 3;
  const int b = x * 4 + (jj >> 3), qt = jj & 7;
  const int q0 = qt * 128, d0 = blockIdx.z * 512;
  const int w = t >> 6, l = t & 63, wm = w >> 2, wd = w & 3, g = l >> 4, ln = l & 15;
  const int lrow = l >> 3, lc8 = (l & 7) * 8, sc = lc8 ^ (lrow << 3);
  const f32x4 fz = {0.f, 0.f, 0.f, 0.f};
  f32x4 acc[4][8];
#pragma unroll
  for (int a = 0; a < 4; a++)
#pragma unroll
    for (int bq = 0; bq < 8; bq++) acc[a][bq] = fz;
  const size_t kbase = (size_t)b * 1024 * 1024;
#pragma unroll 1
  for (int k0 = 0; k0 < 1024; k0 += 64) {
#pragma unroll
    for (int jj2 = 0; jj2 < 2; jj2++) {  // P: 16 chunks
      const int ch = w * 2 + jj2;
      const int row = ch * 8 + lrow;
      gld16(attnw + (size_t)(b * 1024 + q0 + row) * 1024 + k0 + sc, &P[ch * 512]);
    }
#pragma unroll
    for (int jj2 = 0; jj2 < 8; jj2++) {  // KT: 64 chunks
      const int ch = w * 8 + jj2;
      const int row = ch * 8 + lrow;
      gld16(KhiT + kbase + (size_t)(d0 + row) * 1024 + k0 + sc, &KT[ch * 512]);
    }
    __syncthreads();
#pragma unroll
    for (int ks = 0; ks < 2; ks++) {
      const int kc = ks * 32 + g * 8;
      s16x8 a[4], bb[8];
#pragma unroll
      for (int mf = 0; mf < 4; mf++) {
        const int row = wm * 64 + mf * 16 + ln;
        a[mf] = *(const s16x8*)&P[row * 64 + (kc ^ ((row & 7) << 3))];
      }
#pragma unroll
      for (int nf = 0; nf < 8; nf++) {
        const int row = wd * 128 + nf * 16 + ln;
        bb[nf] = *(const s16x8*)&KT[row * 64 + (kc ^ ((row & 7) << 3))];
      }
#pragma unroll
      for (int mf = 0; mf < 4; mf++)
#pragma unroll
        for (int nf = 0; nf < 8; nf++) acc[mf][nf] = MFMA16(a[mf], bb[nf], acc[mf][nf]);
    }
    __syncthreads();
  }
#pragma unroll
  for (int mf = 0; mf < 4; mf++)
#pragma unroll
    for (int nf = 0; nf < 8; nf++)
#pragma unroll
      for (int r = 0; r < 4; r++) {
        const int q = q0 + wm * 64 + mf * 16 + g * 4 + r;
        const int d = d0 + wd * 128 + nf * 16 + ln;
        dout[(size_t)(b * 1024 + q) * 1024 + d] = acc[mf][nf][r];
      }
}

// ================= Tier C: round-1 kernels (fallback, unchanged) =============
__global__ __launch_bounds__(256, 2) void k_qf(const float* __restrict__ Q,
                                               const float* __restrict__ W,
                                               const float* __restrict__ bias,
                                               float* __restrict__ qf) {
  __shared__ __align__(16) short Ah[128 * 64], Al[128 * 64], Bh[128 * 64], Bl[128 * 64];
  const int t = threadIdx.x;
  const int m0 = blockIdx.x * 128, n0 = blockIdx.y * 128;
  const int w = t >> 6, l = t & 63, wm = w >> 1, wn = w & 1, g = l >> 4, ln = l & 15;
  const f32x4 fz = {0.f, 0.f, 0.f, 0.f};
  f32x4 acc[4][4];
#pragma unroll
  for (int a = 0; a < 4; a++)
#pragma unroll
    for (int bq = 0; bq < 4; bq++) acc[a][bq] = fz;
  const int srow = t >> 1, scol = (t & 1) * 32;
#pragma unroll 1
  for (int k0 = 0; k0 < 1024; k0 += 64) {
    const float* sa = Q + (size_t)(m0 + srow) * 1024 + k0 + scol;
    const float* sb = W + (size_t)(n0 + srow) * 1024 + k0 + scol;
#pragma unroll
    for (int c = 0; c < 32; c += 8) {
      s16x8 h, lo;
      cvt8(sa + c, h, lo);
      int si = swz(srow, scol + c);
      *(s16x8*)&Ah[si] = h;
      *(s16x8*)&Al[si] = lo;
    }
#pragma unroll
    for (int c = 0; c < 32; c += 8) {
      s16x8 h, lo;
      cvt8(sb + c, h, lo);
      int si = swz(srow, scol + c);
      *(s16x8*)&Bh[si] = h;
      *(s16x8*)&Bl[si] = lo;
    }
    __syncthreads();
#pragma unroll
    for (int ks = 0; ks < 2; ks++) {
      const int kc = ks * 32 + g * 8;
      s16x8 ah[4], al[4], bh[4], bl[4];
#pragma unroll
      for (int mf = 0; mf < 4; mf++) {
        int si = swz(wm * 64 + mf * 16 + ln, kc);
        ah[mf] = *(s16x8*)&Ah[si];
        al[mf] = *(s16x8*)&Al[si];
      }
#pragma unroll
      for (int nf = 0; nf < 4; nf++) {
        int si = swz(wn * 64 + nf * 16 + ln, kc);
        bh[nf] = *(s16x8*)&Bh[si];
        bl[nf] = *(s16x8*)&Bl[si];
      }
#pragma unroll
      for (int mf = 0; mf < 4; mf++)
#pragma unroll
        for (int nf = 0; nf < 4; nf++) {
          acc[mf][nf] = MFMA16(ah[mf], bh[nf], acc[mf][nf]);
          acc[mf][nf] = MFMA16(ah[mf], bl[nf], acc[mf][nf]);
          acc[mf][nf] = MFMA16(al[mf], bh[nf], acc[mf][nf]);
        }
    }
    __syncthreads();
  }
#pragma unroll
  for (int nf = 0; nf < 4; nf++) {
    const int col = n0 + wn * 64 + nf * 16 + ln;
    const float bv = bias[col];
#pragma unroll
    for (int mf = 0; mf < 4; mf++)
#pragma unroll
      for (int r = 0; r < 4; r++) {
        const int row = m0 + wm * 64 + mf * 16 + g * 4 + r;
        float v = acc[mf][nf][r] + bv;
        qf[(size_t)row * 1024 + col] = v > 0.f ? v : 0.f;
      }
  }
}

__global__ __launch_bounds__(512, 2) void k_attn(const float* __restrict__ Key,
                                                 const float* __restrict__ mask,
                                                 float* __restrict__ dout) {
  __shared__ __align__(16) short qh[64 * 64], qlo[64 * 64], kh[128 * 64], klo[128 * 64];
  __shared__ float mask_s[1024];
  __shared__ float red[4][64];
  const int t = threadIdx.x;
  const int qt = blockIdx.x, b = blockIdx.y;
  const int q0 = qt * 64;
  const int w = t >> 6, l = t & 63, wm = w >> 2, wn = w & 3, g = l >> 4, ln = l & 15;
  for (int i = t; i < 1024; i += 512) mask_s[i] = mask[b * 1024 + i];
  const f32x4 fz = {0.f, 0.f, 0.f, 0.f};
  f32x4 acc[8][2][2];
#pragma unroll
  for (int kt = 0; kt < 8; kt++)
#pragma unroll
    for (int mf = 0; mf < 2; mf++)
#pragma unroll
      for (int nf = 0; nf < 2; nf++) acc[kt][mf][nf] = fz;
  const float* qfb = dout + (size_t)(b * 1024 + q0) * 1024;
  const float* kb = Key + (size_t)b * 1024 * 1024;
  const int qrow = t >> 3, qcol = (t & 7) * 8;
  const int krow = t >> 2, kcol0 = (t & 3) * 16;
#pragma unroll 1
  for (int dc = 0; dc < 16; dc++) {
    {
      s16x8 h, lo;
      cvt8(qfb + (size_t)qrow * 1024 + dc * 64 + qcol, h, lo);
      int si = swz(qrow, qcol);
      *(s16x8*)&qh[si] = h;
      *(s16x8*)&qlo[si] = lo;
    }
#pragma unroll
    for (int kt = 0; kt < 8; kt++) {
      {
        const float* s = kb + (size_t)(kt * 128 + krow) * 1024 + dc * 64 + kcol0;
        s16x8 h, lo;
        cvt8(s, h, lo);
        int si = swz(krow, kcol0);
        *(s16x8*)&kh[si] = h;
        *(s16x8*)&klo[si] = lo;
        cvt8(s + 8, h, lo);
        si = swz(krow, kcol0 + 8);
        *(s16x8*)&kh[si] = h;
        *(s16x8*)&klo[si] = lo;
      }
      __syncthreads();
#pragma unroll
      for (int ks = 0; ks < 2; ks++) {
        const int kc = ks * 32 + g * 8;
        s16x8 ah[2], al2[2], bh[2], bl[2];
#pragma unroll
        for (int mf = 0; mf < 2; mf++) {
          int si = swz(wm * 32 + mf * 16 + ln, kc);
          ah[mf] = *(s16x8*)&qh[si];
          al2[mf] = *(s16x8*)&qlo[si];
        }
#pragma unroll
        for (int nf = 0; nf < 2; nf++) {
          int si = swz(wn * 32 + nf * 16 + ln, kc);
          bh[nf] = *(s16x8*)&kh[si];
          bl[nf] = *(s16x8*)&klo[si];
        }
#pragma unroll
        for (int mf = 0; mf < 2; mf++)
#pragma unroll
          for (int nf = 0; nf < 2; nf++) {
            acc[kt][mf][nf] = MFMA16(ah[mf], bh[nf], acc[kt][mf][nf]);
            acc[kt][mf][nf] = MFMA16(ah[mf], bl[nf], acc[kt][mf][nf]);
            acc[kt][mf][nf] = MFMA16(al2[mf], bh[nf], acc[kt][mf][nf]);
          }
      }
      __syncthreads();
    }
  }
  float rmax[2][4];
#pragma unroll
  for (int mf = 0; mf < 2; mf++)
#pragma unroll
    for (int r = 0; r < 4; r++) rmax[mf][r] = -1e30f;
#pragma unroll
  for (int kt = 0; kt < 8; kt++)
#pragma unroll
    for (int nf = 0; nf < 2; nf++) {
      const int k = kt * 128 + wn * 32 + nf * 16 + ln;
      const bool mk = mask_s[k] != 0.f;
#pragma unroll
      for (int mf = 0; mf < 2; mf++)
#pragma unroll
        for (int r = 0; r < 4; r++)
          if (mk) rmax[mf][r] = fmaxf(rmax[mf][r], acc[kt][mf][nf][r]);
    }
#pragma unroll
  for (int off = 1; off < 16; off <<= 1)
#pragma unroll
    for (int mf = 0; mf < 2; mf++)
#pragma unroll
      for (int r = 0; r < 4; r++) rmax[mf][r] = fmaxf(rmax[mf][r], __shfl_xor(rmax[mf][r], off));
  if (ln == 0) {
#pragma unroll
    for (int mf = 0; mf < 2; mf++)
#pragma unroll
      for (int r = 0; r < 4; r++) red[wn][wm * 32 + mf * 16 + g * 4 + r] = rmax[mf][r];
  }
  __syncthreads();
#pragma unroll
  for (int mf = 0; mf < 2; mf++)
#pragma unroll
    for (int r = 0; r < 4; r++) {
      const int row = wm * 32 + mf * 16 + g * 4 + r;
      rmax[mf][r] = fmaxf(fmaxf(red[0][row], red[1][row]), fmaxf(red[2][row], red[3][row]));
    }
  __syncthreads();
  float rsum[2][4];
#pragma unroll
  for (int mf = 0; mf < 2; mf++)
#pragma unroll
    for (int r = 0; r < 4; r++) rsum[mf][r] = 0.f;
#pragma unroll
  for (int kt = 0; kt < 8; kt++)
#pragma unroll
    for (int nf = 0; nf < 2; nf++) {
      const int k = kt * 128 + wn * 32 + nf * 16 + ln;
      const bool mk = mask_s[k] != 0.f;
#pragma unroll
      for (int mf = 0; mf < 2; mf++)
#pragma unroll
        for (int r = 0; r < 4; r++)
          if (mk) rsum[mf][r] += __expf(acc[kt][mf][nf][r] - rmax[mf][r]);
    }
#pragma unroll
  for (int off = 1; off < 16; off <<= 1)
#pragma unroll
    for (int mf = 0; mf < 2; mf++)
#pragma unroll
      for (int r = 0; r < 4; r++) rsum[mf][r] += __shfl_xor(rsum[mf][r], off);
  if (ln == 0) {
#pragma unroll
    for (int mf = 0; mf < 2; mf++)
#pragma unroll
      for (int r = 0; r < 4; r++) red[wn][wm * 32 + mf * 16 + g * 4 + r] = rsum[mf][r];
  }
  __syncthreads();
  float rinv[2][4];
#pragma unroll
  for (int mf = 0; mf < 2; mf++)
#pragma unroll
    for (int r = 0; r < 4; r++) {
      const int row = wm * 32 + mf * 16 + g * 4 + r;
      rinv[mf][r] = 1.f / (red[0][row] + red[1][row] + red[2][row] + red[3][row]);
    }
  char* oc = (char*)dout;
#pragma unroll
  for (int kt = 0; kt < 8; kt++)
#pragma unroll
    for (int nf = 0; nf < 2; nf++) {
      const int k = kt * 128 + wn * 32 + nf * 16 + ln;
      const bool mk = mask_s[k] != 0.f;
#pragma unroll
      for (int mf = 0; mf < 2; mf++)
#pragma unroll
        for (int r = 0; r < 4; r++) {
          const int q = q0 + wm * 32 + mf * 16 + g * 4 + r;
          float p = mk ? __expf(acc[kt][mf][nf][r] - rmax[mf][r]) * rinv[mf][r] : 0.f;
          *(unsigned short*)(oc + (size_t)(b * 1024 + q) * 4096 + 2048 + k * 2) = f2bf(p);
        }
    }
}

__global__ __launch_bounds__(512, 2) void k_pv(const float* __restrict__ Key,
                                               float* __restrict__ dout, const int dh) {
  __shared__ __align__(16) short P[128 * 64];
  __shared__ __align__(16) short KT[512 * 64];
  const int t = threadIdx.x;
  const int qt = blockIdx.x, b = blockIdx.y;
  const int q0 = qt * 128, d0 = dh * 512;
  const int w = t >> 6, l = t & 63, wm = w >> 2, wd = w & 3, g = l >> 4, ln = l & 15;
  const f32x4 fz = {0.f, 0.f, 0.f, 0.f};
  f32x4 acc[4][8];
#pragma unroll
  for (int a = 0; a < 4; a++)
#pragma unroll
    for (int bq = 0; bq < 8; bq++) acc[a][bq] = fz;
  const char* ab = (const char*)dout;
  const int prow = t >> 2, pc0 = (t & 3) * 16;
#pragma unroll 1
  for (int k0 = 0; k0 < 1024; k0 += 64) {
    {
      const unsigned short* s =
          (const unsigned short*)(ab + (size_t)(b * 1024 + q0 + prow) * 4096 + 2048) + k0 + pc0;
      s16x8 p0 = *(const s16x8*)s, p1 = *(const s16x8*)(s + 8);
      *(s16x8*)&P[swz(prow, pc0)] = p0;
      *(s16x8*)&P[swz(prow, pc0 + 8)] = p1;
    }
    {
      const float* ksrc = Key + (size_t)b * 1024 * 1024 + (size_t)k0 * 1024 + d0 + t;
#pragma unroll
      for (int kg = 0; kg < 8; kg++) {
        s16x8 h;
#pragma unroll
        for (int jx = 0; jx < 8; jx++) h[jx] = (short)f2bf(ksrc[(size_t)(kg * 8 + jx) * 1024]);
        *(s16x8*)&KT[swz(t, kg * 8)] = h;
      }
    }
    __syncthreads();
#pragma unroll
    for (int ks = 0; ks < 2; ks++) {
      const int kc = ks * 32 + g * 8;
      s16x8 a[4], bb[8];
#pragma unroll
      for (int mf = 0; mf < 4; mf++) a[mf] = *(s16x8*)&P[swz(wm * 64 + mf * 16 + ln, kc)];
#pragma unroll
      for (int nf = 0; nf < 8; nf++) bb[nf] = *(s16x8*)&KT[swz(wd * 128 + nf * 16 + ln, kc)];
#pragma unroll
      for (int mf = 0; mf < 4; mf++)
#pragma unroll
        for (int nf = 0; nf < 8; nf++) acc[mf][nf] = MFMA16(a[mf], bb[nf], acc[mf][nf]);
    }
    __syncthreads();
  }
#pragma unroll
  for (int mf = 0; mf < 4; mf++)
#pragma unroll
    for (int nf = 0; nf < 8; nf++)
#pragma unroll
      for (int r = 0; r < 4; r++) {
        const int q = q0 + wm * 64 + mf * 16 + g * 4 + r;
        const int d = d0 + wd * 128 + nf * 16 + ln;
        dout[(size_t)(b * 1024 + q) * 1024 + d] = acc[mf][nf][r];
      }
}

extern "C" void kernel_launch(void* const* d_in, const int* in_sizes, int n_in,
                              void* d_out, int out_size, void* d_ws, size_t ws_size,
                              hipStream_t stream) {
  const float* Q = (const float*)d_in[0];
  const float* K = (const float*)d_in[1];
  const float* M = (const float*)d_in[2];
  const float* W = (const float*)d_in[3];
  const float* bias = (const float*)d_in[4];
  float* out = (float*)d_out;
  char* wsb = (char*)d_ws;
  (void)in_sizes; (void)n_in; (void)out_size;

  if (ws_size >= WS_TIER_A) {
    unsigned short* Khi = (unsigned short*)(wsb + OFF_KHI);
    unsigned short* Klo = (unsigned short*)(wsb + OFF_KLO);
    unsigned short* KhiT = (unsigned short*)(wsb + OFF_KHIT);
    unsigned short* Qhi = (unsigned short*)(wsb + OFF_QHI);
    unsigned short* Qlo = (unsigned short*)(wsb + OFF_QLO);
    unsigned short* Whi = (unsigned short*)(wsb + OFF_WHI);
    unsigned short* Wlo = (unsigned short*)(wsb + OFF_WLO);
    unsigned short* attnw = Qhi;  // Qhi/Qlo dead after k_qf2; reuse for attn
    k_cvt_k<<<dim3(16, 16, 32), 256, 0, stream>>>(K, Khi, Klo, KhiT);
    k_cvt_pair<<<16384, 256, 0, stream>>>(Q, Qhi, Qlo, 4194304);
    k_cvt_pair<<<512, 256, 0, stream>>>(W, Whi, Wlo, 131072);
    k_qf2<<<dim3(256, 8), 256, 0, stream>>>(Qhi, Qlo, Whi, Wlo, bias, out);
    k_attn2<<<dim3(16, 32), 512, 0, stream>>>(Khi, Klo, M, (const unsigned short*)out, attnw);
    k_pv2<<<dim3(8, 32, 2), 512, 0, stream>>>(KhiT, attnw, out);
  } else {
    k_qf<<<dim3(256, 8), 256, 0, stream>>>(Q, W, bias, out);
    k_attn<<<dim3(16, 32), 512, 0, stream>>>(K, M, out);
    k_pv<<<dim3(8, 32), 512, 0, stream>>>(K, out, 0);
    k_pv<<<dim3(8, 32), 512, 0, stream>>>(K, out, 1);
  }
}

// Round 6
// 727.744 us; speedup vs baseline: 1.2289x; 1.2289x over previous
//
#include <hip/hip_runtime.h>
#include <hip/hip_bf16.h>

// WordSentAtt: qf = relu(Q@W^T + b); S = qf@K^T (masked); attn = softmax; O = attn@K
// B=32, Lq=Lk=D=1024, f32 in/out. Split-bf16 (hi/lo) MFMA for qf and S.
// R6: attn2 = R4 geometry (BK=64, 64KB dbuf, conflict-free pattern) +
//   R5's coalesced frag-ordered q loads (regs) + T4 counted-vmcnt pipeline:
//   per segment {vmcnt(4|8|0); s_barrier; sched_barrier; issue stage(s+1);
//   ds_read; 24 MFMA}. No vmcnt(0) drain inside the loop. Key facts from R5:
//   occupancy is 1 block/CU (S-in-regs = 128 AGPR + ~120 VGPR), so all
//   latency hiding must come from within the block -> T4.

typedef __attribute__((ext_vector_type(4))) float f32x4;
typedef __attribute__((ext_vector_type(8))) short s16x8;

#define MFMA16(a, b, c) __builtin_amdgcn_mfma_f32_16x16x32_bf16((a), (b), (c), 0, 0, 0)

__device__ __forceinline__ unsigned short f2bf(float x) {
  unsigned u = __builtin_bit_cast(unsigned, x);
  return (unsigned short)((u + 0x7FFFu + ((u >> 16) & 1u)) >> 16);
}
__device__ __forceinline__ float bf2f(unsigned short h) {
  return __builtin_bit_cast(float, ((unsigned)h) << 16);
}
__device__ __forceinline__ int swz(int row, int col) {
  return (row * 64 + col) ^ ((row & 7) << 3);
}
__device__ __forceinline__ void cvt8(const float* __restrict__ s, s16x8& h8, s16x8& l8) {
  f32x4 a = *(const f32x4*)s;
  f32x4 b = *(const f32x4*)(s + 4);
#pragma unroll
  for (int i = 0; i < 8; i++) {
    float v = (i < 4) ? a[i] : b[i - 4];
    unsigned short hu = f2bf(v);
    unsigned short lu = f2bf(v - bf2f(hu));
    h8[i] = (short)hu;
    l8[i] = (short)lu;
  }
}
__device__ __forceinline__ void gld16(const void* g, void* lds) {
  __builtin_amdgcn_global_load_lds((const __attribute__((address_space(1))) unsigned int*)g,
                                   (__attribute__((address_space(3))) unsigned int*)lds, 16, 0, 0);
}

// ws layout (bytes)
#define OFF_KHI 0ULL
#define OFF_KLO 67108864ULL
#define OFF_KHIT 134217728ULL
#define OFF_QHI 201326592ULL  // qf2 inputs Qhi/Qlo; attn bf16 reuses QHI after qf2
#define OFF_QLO 268435456ULL
#define OFF_WHI 335544320ULL
#define OFF_WLO 337641472ULL
#define WS_TIER_A 339738624ULL
#define QA_LO 33554432ULL  // u16 offset of lo plane inside d_out frag layout

// ================= pre-convert kernels =================
__global__ __launch_bounds__(256) void k_cvt_pair(const float* __restrict__ src,
                                                  unsigned short* __restrict__ hi,
                                                  unsigned short* __restrict__ lo, int n8) {
  int i = blockIdx.x * 256 + threadIdx.x;
  if (i >= n8) return;
  s16x8 h, l;
  cvt8(src + (size_t)i * 8, h, l);
  *(s16x8*)(hi + (size_t)i * 8) = h;
  *(s16x8*)(lo + (size_t)i * 8) = l;
}

__global__ __launch_bounds__(256) void k_cvt_k(const float* __restrict__ K,
                                               unsigned short* __restrict__ Khi,
                                               unsigned short* __restrict__ Klo,
                                               unsigned short* __restrict__ KhiT) {
  __shared__ unsigned T[64 * 65];
  const int t = threadIdx.x;
  const int db0 = blockIdx.x * 64, kb0 = blockIdx.y * 64, b = blockIdx.z;
  const size_t base = (size_t)b * 1024 * 1024;
#pragma unroll
  for (int i = 0; i < 2; i++) {
    const int r = (t >> 3) + i * 32, c0 = (t & 7) * 8;
    s16x8 h, l;
    cvt8(K + base + (size_t)(kb0 + r) * 1024 + db0 + c0, h, l);
    *(s16x8*)(Khi + base + (size_t)(kb0 + r) * 1024 + db0 + c0) = h;
    *(s16x8*)(Klo + base + (size_t)(kb0 + r) * 1024 + db0 + c0) = l;
#pragma unroll
    for (int j = 0; j < 8; j++)
      T[r * 65 + c0 + j] = ((unsigned)(unsigned short)h[j] << 16) | (unsigned short)l[j];
  }
  __syncthreads();
#pragma unroll
  for (int i = 0; i < 2; i++) {
    const int rd = (t >> 3) + i * 32, ck0 = (t & 7) * 8;
    s16x8 h;
#pragma unroll
    for (int j = 0; j < 8; j++) h[j] = (short)(unsigned short)(T[(ck0 + j) * 65 + rd] >> 16);
    *(s16x8*)(KhiT + base + (size_t)(db0 + rd) * 1024 + kb0 + ck0) = h;
  }
}

// ================= qf GEMM -> fragment-ordered output =================
// grid (256,8), 256 thr = 4 waves (2x2). 128x128 tile, BK=64.
// Output layout (u16, in d_out): hi[qblk][kchunk32][lane64][8], lo at +QA_LO.
__global__ __launch_bounds__(256, 2) void k_qf2(const unsigned short* __restrict__ Qhi,
                                                const unsigned short* __restrict__ Qlo,
                                                const unsigned short* __restrict__ Whi,
                                                const unsigned short* __restrict__ Wlo,
                                                const float* __restrict__ bias,
                                                float* __restrict__ outp) {
  __shared__ __align__(16) unsigned short Ah[128 * 64], Al[128 * 64], Bh[128 * 64], Bl[128 * 64];
  const int t = threadIdx.x;
  const int i = blockIdx.x + blockIdx.y * 256;
  const int x = i & 7, j = i >> 3;
  const int n0 = (j & 7) * 128;
  const int m0 = (x * 32 + (j >> 3)) * 128;
  const int w = t >> 6, l = t & 63, wm = w >> 1, wn = w & 1, g = l >> 4, ln = l & 15;
  const int lrow = l >> 3, lc8 = (l & 7) * 8;
  const f32x4 fz = {0.f, 0.f, 0.f, 0.f};
  f32x4 acc[4][4];
#pragma unroll
  for (int a = 0; a < 4; a++)
#pragma unroll
    for (int bq = 0; bq < 4; bq++) acc[a][bq] = fz;
#pragma unroll 1
  for (int k0 = 0; k0 < 1024; k0 += 64) {
#pragma unroll
    for (int jj = 0; jj < 4; jj++) {
      const int ch = w * 4 + jj;
      const int row = ch * 8 + lrow;
      const int sc = lc8 ^ (lrow << 3);
      gld16(Qhi + (size_t)(m0 + row) * 1024 + k0 + sc, &Ah[ch * 512]);
      gld16(Qlo + (size_t)(m0 + row) * 1024 + k0 + sc, &Al[ch * 512]);
      gld16(Whi + (size_t)(n0 + row) * 1024 + k0 + sc, &Bh[ch * 512]);
      gld16(Wlo + (size_t)(n0 + row) * 1024 + k0 + sc, &Bl[ch * 512]);
    }
    __syncthreads();
#pragma unroll
    for (int ks = 0; ks < 2; ks++) {
      const int kc = ks * 32 + g * 8;
      s16x8 ah[4], al[4], bh[4], bl[4];
#pragma unroll
      for (int mf = 0; mf < 4; mf++) {
        const int row = wm * 64 + mf * 16 + ln;
        const int idx = row * 64 + (kc ^ ((row & 7) << 3));
        ah[mf] = *(const s16x8*)&Ah[idx];
        al[mf] = *(const s16x8*)&Al[idx];
      }
#pragma unroll
      for (int nf = 0; nf < 4; nf++) {
        const int row = wn * 64 + nf * 16 + ln;
        const int idx = row * 64 + (kc ^ ((row & 7) << 3));
        bh[nf] = *(const s16x8*)&Bh[idx];
        bl[nf] = *(const s16x8*)&Bl[idx];
      }
#pragma unroll
      for (int mf = 0; mf < 4; mf++)
#pragma unroll
        for (int nf = 0; nf < 4; nf++) {
          acc[mf][nf] = MFMA16(ah[mf], bh[nf], acc[mf][nf]);
          acc[mf][nf] = MFMA16(ah[mf], bl[nf], acc[mf][nf]);
          acc[mf][nf] = MFMA16(al[mf], bh[nf], acc[mf][nf]);
        }
    }
    __syncthreads();
  }
  unsigned short* qA = (unsigned short*)outp;
#pragma unroll
  for (int nf = 0; nf < 4; nf++) {
    const int c = n0 + wn * 64 + nf * 16 + ln;
    const float bv = bias[c];
    const int kchunk = c >> 5, lhib = ((c >> 3) & 3) << 4, jj = c & 7;
#pragma unroll
    for (int mf = 0; mf < 4; mf++)
#pragma unroll
      for (int r = 0; r < 4; r++) {
        const int R = m0 + wm * 64 + mf * 16 + g * 4 + r;
        float v = acc[mf][nf][r] + bv;
        v = v > 0.f ? v : 0.f;
        unsigned short h = f2bf(v);
        const size_t fo = (((size_t)(R >> 4) * 32 + kchunk) * 64 + ((R & 15) + lhib)) * 8 + jj;
        qA[fo] = h;
        qA[QA_LO + fo] = f2bf(v - bf2f(h));
      }
  }
}

// ================= score GEMM + masked softmax (R6: T4 pipeline) =============
// grid (16,32), 512 thr = 8 waves (2 wm x 4 wn). S[64][1024] in regs (AGPR).
// 128 segments (16 dc x 8 kt) x 24 MFMA/wave. K dbuf 64KB. Counted vmcnt.
__global__ __launch_bounds__(512, 2) void k_attn2(const unsigned short* __restrict__ Khi,
                                                  const unsigned short* __restrict__ Klo,
                                                  const float* __restrict__ mask,
                                                  const unsigned short* __restrict__ qA,
                                                  unsigned short* __restrict__ attnw) {
  __shared__ __align__(16) unsigned short kbuf[2][2][128 * 64];  // [buf][plane]
  __shared__ float mask_s[1024];
  __shared__ float red[4][64];
  const int t = threadIdx.x;
  const int i = blockIdx.y * 16 + blockIdx.x;
  const int x = i & 7, jj = i >> 3;
  const int b = x * 4 + (jj >> 4), qt = jj & 15;
  const int q0 = qt * 64;
  const int w = t >> 6, l = t & 63, wm = w >> 2, wn = w & 3, g = l >> 4, ln = l & 15;
  const int lrow = l >> 3, lc8 = (l & 7) * 8, sc = lc8 ^ (lrow << 3);
  for (int ii = t; ii < 1024; ii += 512) mask_s[ii] = mask[b * 1024 + ii];
  const f32x4 fz = {0.f, 0.f, 0.f, 0.f};
  f32x4 acc[8][2][2];
#pragma unroll
  for (int kt = 0; kt < 8; kt++)
#pragma unroll
    for (int mf = 0; mf < 2; mf++)
#pragma unroll
      for (int nf = 0; nf < 2; nf++) acc[kt][mf][nf] = fz;
  const size_t kbase = (size_t)b * 1024 * 1024;
  const int qblk0 = (b * 1024 + q0) >> 4;

  // stage one 128x64 K tile (hi+lo): 16 chunks/plane, 2/wave; 4 gld16/wave
  auto stageK = [&](int buf, int kt, int dc) {
#pragma unroll
    for (int jj2 = 0; jj2 < 2; jj2++) {
      const int ch = w * 2 + jj2;
      const int row = ch * 8 + lrow;
      const size_t go = kbase + (size_t)(kt * 128 + row) * 1024 + dc * 64 + sc;
      gld16(Khi + go, &kbuf[buf][0][ch * 512]);
      gld16(Klo + go, &kbuf[buf][1][ch * 512]);
    }
  };

  stageK(0, 0, 0);
  __syncthreads();  // full drain once: stage(0) + mask_s visible
#pragma unroll 1
  for (int dc = 0; dc < 16; dc++) {
    // q-frags for this 64-col band: coalesced loads (issued 1 segment early)
    s16x8 qh[2][2], ql[2][2];
#pragma unroll
    for (int mf = 0; mf < 2; mf++) {
      const int qb = qblk0 + wm * 2 + mf;
#pragma unroll
      for (int ks = 0; ks < 2; ks++) {
        const size_t fo = (((size_t)qb * 32 + dc * 2 + ks) * 64 + l) * 8;
        qh[mf][ks] = *(const s16x8*)(qA + fo);
        ql[mf][ks] = *(const s16x8*)(qA + QA_LO + fo);
      }
    }
#pragma unroll  // full: acc[kt] must be statically indexed (rule #20)
    for (int kt = 0; kt < 8; kt++) {
      const int snum = dc * 8 + kt;
      // P1: wait for stage(snum) (4 loads). At dc boundary 8 q-loads are
      // younger than stage(snum) -> vmcnt(8); last segment -> drain.
      if (snum == 127) {
        asm volatile("s_waitcnt vmcnt(0)" ::: "memory");
      } else if (kt == 0) {
        asm volatile("s_waitcnt vmcnt(8)" ::: "memory");
      } else {
        asm volatile("s_waitcnt vmcnt(4)" ::: "memory");
      }
      __builtin_amdgcn_s_barrier();
      __builtin_amdgcn_sched_barrier(0);  // keep stage-issue BELOW the barrier
      // P2: issue next stage (into the buffer everyone just finished reading)
      if (snum < 127) {
        const int nkt = (kt + 1) & 7;
        const int ndc = (kt == 7) ? dc + 1 : dc;
        stageK((snum + 1) & 1, nkt, ndc);
      }
      const int cur = snum & 1;
#pragma unroll
      for (int ks = 0; ks < 2; ks++) {
        const int kc = ks * 32 + g * 8;
        s16x8 bh[2], bl[2];
#pragma unroll
        for (int nf = 0; nf < 2; nf++) {
          const int row = wn * 32 + nf * 16 + ln;
          const int idx = row * 64 + (kc ^ ((row & 7) << 3));
          bh[nf] = *(const s16x8*)&kbuf[cur][0][idx];
          bl[nf] = *(const s16x8*)&kbuf[cur][1][idx];
        }
#pragma unroll
        for (int mf = 0; mf < 2; mf++)
#pragma unroll
          for (int nf = 0; nf < 2; nf++) {
            acc[kt][mf][nf] = MFMA16(qh[mf][ks], bh[nf], acc[kt][mf][nf]);
            acc[kt][mf][nf] = MFMA16(qh[mf][ks], bl[nf], acc[kt][mf][nf]);
            acc[kt][mf][nf] = MFMA16(ql[mf][ks], bh[nf], acc[kt][mf][nf]);
          }
      }
      // no trailing barrier: next P1's barrier protects buffer reuse
    }
  }
  __syncthreads();
  // ---- masked softmax ----
  float rmax[2][4];
#pragma unroll
  for (int mf = 0; mf < 2; mf++)
#pragma unroll
    for (int r = 0; r < 4; r++) rmax[mf][r] = -1e30f;
#pragma unroll
  for (int kt = 0; kt < 8; kt++)
#pragma unroll
    for (int nf = 0; nf < 2; nf++) {
      const int k = kt * 128 + wn * 32 + nf * 16 + ln;
      const bool mk = mask_s[k] != 0.f;
#pragma unroll
      for (int mf = 0; mf < 2; mf++)
#pragma unroll
        for (int r = 0; r < 4; r++)
          if (mk) rmax[mf][r] = fmaxf(rmax[mf][r], acc[kt][mf][nf][r]);
    }
#pragma unroll
  for (int off = 1; off < 16; off <<= 1)
#pragma unroll
    for (int mf = 0; mf < 2; mf++)
#pragma unroll
      for (int r = 0; r < 4; r++) rmax[mf][r] = fmaxf(rmax[mf][r], __shfl_xor(rmax[mf][r], off));
  if (ln == 0) {
#pragma unroll
    for (int mf = 0; mf < 2; mf++)
#pragma unroll
      for (int r = 0; r < 4; r++) red[wn][wm * 32 + mf * 16 + g * 4 + r] = rmax[mf][r];
  }
  __syncthreads();
#pragma unroll
  for (int mf = 0; mf < 2; mf++)
#pragma unroll
    for (int r = 0; r < 4; r++) {
      const int row = wm * 32 + mf * 16 + g * 4 + r;
      rmax[mf][r] = fmaxf(fmaxf(red[0][row], red[1][row]), fmaxf(red[2][row], red[3][row]));
    }
  __syncthreads();
  float rsum[2][4];
#pragma unroll
  for (int mf = 0; mf < 2; mf++)
#pragma unroll
    for (int r = 0; r < 4; r++) rsum[mf][r] = 0.f;
#pragma unroll
  for (int kt = 0; kt < 8; kt++)
#pragma unroll
    for (int nf = 0; nf < 2; nf++) {
      const int k = kt * 128 + wn * 32 + nf * 16 + ln;
      const bool mk = mask_s[k] != 0.f;
#pragma unroll
      for (int mf = 0; mf < 2; mf++)
#pragma unroll
        for (int r = 0; r < 4; r++)
          if (mk) rsum[mf][r] += __expf(acc[kt][mf][nf][r] - rmax[mf][r]);
    }
#pragma unroll
  for (int off = 1; off < 16; off <<= 1)
#pragma unroll
    for (int mf = 0; mf < 2; mf++)
#pragma unroll
      for (int r = 0; r < 4; r++) rsum[mf][r] += __shfl_xor(rsum[mf][r], off);
  if (ln == 0) {
#pragma unroll
    for (int mf = 0; mf < 2; mf++)
#pragma unroll
      for (int r = 0; r < 4; r++) red[wn][wm * 32 + mf * 16 + g * 4 + r] = rsum[mf][r];
  }
  __syncthreads();
  float rinv[2][4];
#pragma unroll
  for (int mf = 0; mf < 2; mf++)
#pragma unroll
    for (int r = 0; r < 4; r++) {
      const int row = wm * 32 + mf * 16 + g * 4 + r;
      rinv[mf][r] = 1.f / (red[0][row] + red[1][row] + red[2][row] + red[3][row]);
    }
#pragma unroll
  for (int kt = 0; kt < 8; kt++)
#pragma unroll
    for (int nf = 0; nf < 2; nf++) {
      const int k = kt * 128 + wn * 32 + nf * 16 + ln;
      const bool mk = mask_s[k] != 0.f;
#pragma unroll
      for (int mf = 0; mf < 2; mf++)
#pragma unroll
        for (int r = 0; r < 4; r++) {
          const int q = q0 + wm * 32 + mf * 16 + g * 4 + r;
          float p = mk ? __expf(acc[kt][mf][nf][r] - rmax[mf][r]) * rinv[mf][r] : 0.f;
          attnw[(size_t)(b * 1024 + q) * 1024 + k] = f2bf(p);
        }
    }
}

// ================= O = attn @ K via KhiT (single launch, z = d-half) ==========
__global__ __launch_bounds__(512, 2) void k_pv2(const unsigned short* __restrict__ KhiT,
                                                const unsigned short* __restrict__ attnw,
                                                float* __restrict__ dout) {
  __shared__ __align__(16) unsigned short P[128 * 64];
  __shared__ __align__(16) unsigned short KT[512 * 64];
  const int t = threadIdx.x;
  const int i = blockIdx.y * 8 + blockIdx.x;
  const int x = i & 7, jj = i >> 3;
  const int b = x * 4 + (jj >> 3), qt = jj & 7;
  const int q0 = qt * 128, d0 = blockIdx.z * 512;
  const int w = t >> 6, l = t & 63, wm = w >> 2, wd = w & 3, g = l >> 4, ln = l & 15;
  const int lrow = l >> 3, lc8 = (l & 7) * 8, sc = lc8 ^ (lrow << 3);
  const f32x4 fz = {0.f, 0.f, 0.f, 0.f};
  f32x4 acc[4][8];
#pragma unroll
  for (int a = 0; a < 4; a++)
#pragma unroll
    for (int bq = 0; bq < 8; bq++) acc[a][bq] = fz;
  const size_t kbase = (size_t)b * 1024 * 1024;
#pragma unroll 1
  for (int k0 = 0; k0 < 1024; k0 += 64) {
#pragma unroll
    for (int jj2 = 0; jj2 < 2; jj2++) {
      const int ch = w * 2 + jj2;
      const int row = ch * 8 + lrow;
      gld16(attnw + (size_t)(b * 1024 + q0 + row) * 1024 + k0 + sc, &P[ch * 512]);
    }
#pragma unroll
    for (int jj2 = 0; jj2 < 8; jj2++) {
      const int ch = w * 8 + jj2;
      const int row = ch * 8 + lrow;
      gld16(KhiT + kbase + (size_t)(d0 + row) * 1024 + k0 + sc, &KT[ch * 512]);
    }
    __syncthreads();
#pragma unroll
    for (int ks = 0; ks < 2; ks++) {
      const int kc = ks * 32 + g * 8;
      s16x8 a[4], bb[8];
#pragma unroll
      for (int mf = 0; mf < 4; mf++) {
        const int row = wm * 64 + mf * 16 + ln;
        a[mf] = *(const s16x8*)&P[row * 64 + (kc ^ ((row & 7) << 3))];
      }
#pragma unroll
      for (int nf = 0; nf < 8; nf++) {
        const int row = wd * 128 + nf * 16 + ln;
        bb[nf] = *(const s16x8*)&KT[row * 64 + (kc ^ ((row & 7) << 3))];
      }
#pragma unroll
      for (int mf = 0; mf < 4; mf++)
#pragma unroll
        for (int nf = 0; nf < 8; nf++) acc[mf][nf] = MFMA16(a[mf], bb[nf], acc[mf][nf]);
    }
    __syncthreads();
  }
#pragma unroll
  for (int mf = 0; mf < 4; mf++)
#pragma unroll
    for (int nf = 0; nf < 8; nf++)
#pragma unroll
      for (int r = 0; r < 4; r++) {
        const int q = q0 + wm * 64 + mf * 16 + g * 4 + r;
        const int d = d0 + wd * 128 + nf * 16 + ln;
        dout[(size_t)(b * 1024 + q) * 1024 + d] = acc[mf][nf][r];
      }
}

// ================= Tier C: round-1 kernels (fallback, unchanged) =============
__global__ __launch_bounds__(256, 2) void k_qf(const float* __restrict__ Q,
                                               const float* __restrict__ W,
                                               const float* __restrict__ bias,
                                               float* __restrict__ qf) {
  __shared__ __align__(16) short Ah[128 * 64], Al[128 * 64], Bh[128 * 64], Bl[128 * 64];
  const int t = threadIdx.x;
  const int m0 = blockIdx.x * 128, n0 = blockIdx.y * 128;
  const int w = t >> 6, l = t & 63, wm = w >> 1, wn = w & 1, g = l >> 4, ln = l & 15;
  const f32x4 fz = {0.f, 0.f, 0.f, 0.f};
  f32x4 acc[4][4];
#pragma unroll
  for (int a = 0; a < 4; a++)
#pragma unroll
    for (int bq = 0; bq < 4; bq++) acc[a][bq] = fz;
  const int srow = t >> 1, scol = (t & 1) * 32;
#pragma unroll 1
  for (int k0 = 0; k0 < 1024; k0 += 64) {
    const float* sa = Q + (size_t)(m0 + srow) * 1024 + k0 + scol;
    const float* sb = W + (size_t)(n0 + srow) * 1024 + k0 + scol;
#pragma unroll
    for (int c = 0; c < 32; c += 8) {
      s16x8 h, lo;
      cvt8(sa + c, h, lo);
      int si = swz(srow, scol + c);
      *(s16x8*)&Ah[si] = h;
      *(s16x8*)&Al[si] = lo;
    }
#pragma unroll
    for (int c = 0; c < 32; c += 8) {
      s16x8 h, lo;
      cvt8(sb + c, h, lo);
      int si = swz(srow, scol + c);
      *(s16x8*)&Bh[si] = h;
      *(s16x8*)&Bl[si] = lo;
    }
    __syncthreads();
#pragma unroll
    for (int ks = 0; ks < 2; ks++) {
      const int kc = ks * 32 + g * 8;
      s16x8 ah[4], al[4], bh[4], bl[4];
#pragma unroll
      for (int mf = 0; mf < 4; mf++) {
        int si = swz(wm * 64 + mf * 16 + ln, kc);
        ah[mf] = *(s16x8*)&Ah[si];
        al[mf] = *(s16x8*)&Al[si];
      }
#pragma unroll
      for (int nf = 0; nf < 4; nf++) {
        int si = swz(wn * 64 + nf * 16 + ln, kc);
        bh[nf] = *(s16x8*)&Bh[si];
        bl[nf] = *(s16x8*)&Bl[si];
      }
#pragma unroll
      for (int mf = 0; mf < 4; mf++)
#pragma unroll
        for (int nf = 0; nf < 4; nf++) {
          acc[mf][nf] = MFMA16(ah[mf], bh[nf], acc[mf][nf]);
          acc[mf][nf] = MFMA16(ah[mf], bl[nf], acc[mf][nf]);
          acc[mf][nf] = MFMA16(al[mf], bh[nf], acc[mf][nf]);
        }
    }
    __syncthreads();
  }
#pragma unroll
  for (int nf = 0; nf < 4; nf++) {
    const int col = n0 + wn * 64 + nf * 16 + ln;
    const float bv = bias[col];
#pragma unroll
    for (int mf = 0; mf < 4; mf++)
#pragma unroll
      for (int r = 0; r < 4; r++) {
        const int row = m0 + wm * 64 + mf * 16 + g * 4 + r;
        float v = acc[mf][nf][r] + bv;
        qf[(size_t)row * 1024 + col] = v > 0.f ? v : 0.f;
      }
  }
}

__global__ __launch_bounds__(512, 2) void k_attn(const float* __restrict__ Key,
                                                 const float* __restrict__ mask,
                                                 float* __restrict__ dout) {
  __shared__ __align__(16) short qh[64 * 64], qlo[64 * 64], kh[128 * 64], klo[128 * 64];
  __shared__ float mask_s[1024];
  __shared__ float red[4][64];
  const int t = threadIdx.x;
  const int qt = blockIdx.x, b = blockIdx.y;
  const int q0 = qt * 64;
  const int w = t >> 6, l = t & 63, wm = w >> 2, wn = w & 3, g = l >> 4, ln = l & 15;
  for (int i = t; i < 1024; i += 512) mask_s[i] = mask[b * 1024 + i];
  const f32x4 fz = {0.f, 0.f, 0.f, 0.f};
  f32x4 acc[8][2][2];
#pragma unroll
  for (int kt = 0; kt < 8; kt++)
#pragma unroll
    for (int mf = 0; mf < 2; mf++)
#pragma unroll
      for (int nf = 0; nf < 2; nf++) acc[kt][mf][nf] = fz;
  const float* qfb = dout + (size_t)(b * 1024 + q0) * 1024;
  const float* kb = Key + (size_t)b * 1024 * 1024;
  const int qrow = t >> 3, qcol = (t & 7) * 8;
  const int krow = t >> 2, kcol0 = (t & 3) * 16;
#pragma unroll 1
  for (int dc = 0; dc < 16; dc++) {
    {
      s16x8 h, lo;
      cvt8(qfb + (size_t)qrow * 1024 + dc * 64 + qcol, h, lo);
      int si = swz(qrow, qcol);
      *(s16x8*)&qh[si] = h;
      *(s16x8*)&qlo[si] = lo;
    }
#pragma unroll
    for (int kt = 0; kt < 8; kt++) {
      {
        const float* s = kb + (size_t)(kt * 128 + krow) * 1024 + dc * 64 + kcol0;
        s16x8 h, lo;
        cvt8(s, h, lo);
        int si = swz(krow, kcol0);
        *(s16x8*)&kh[si] = h;
        *(s16x8*)&klo[si] = lo;
        cvt8(s + 8, h, lo);
        si = swz(krow, kcol0 + 8);
        *(s16x8*)&kh[si] = h;
        *(s16x8*)&klo[si] = lo;
      }
      __syncthreads();
#pragma unroll
      for (int ks = 0; ks < 2; ks++) {
        const int kc = ks * 32 + g * 8;
        s16x8 ah[2], al2[2], bh[2], bl[2];
#pragma unroll
        for (int mf = 0; mf < 2; mf++) {
          int si = swz(wm * 32 + mf * 16 + ln, kc);
          ah[mf] = *(s16x8*)&qh[si];
          al2[mf] = *(s16x8*)&qlo[si];
        }
#pragma unroll
        for (int nf = 0; nf < 2; nf++) {
          int si = swz(wn * 32 + nf * 16 + ln, kc);
          bh[nf] = *(s16x8*)&kh[si];
          bl[nf] = *(s16x8*)&klo[si];
        }
#pragma unroll
        for (int mf = 0; mf < 2; mf++)
#pragma unroll
          for (int nf = 0; nf < 2; nf++) {
            acc[kt][mf][nf] = MFMA16(ah[mf], bh[nf], acc[kt][mf][nf]);
            acc[kt][mf][nf] = MFMA16(ah[mf], bl[nf], acc[kt][mf][nf]);
            acc[kt][mf][nf] = MFMA16(al2[mf], bh[nf], acc[kt][mf][nf]);
          }
      }
      __syncthreads();
    }
  }
  float rmax[2][4];
#pragma unroll
  for (int mf = 0; mf < 2; mf++)
#pragma unroll
    for (int r = 0; r < 4; r++) rmax[mf][r] = -1e30f;
#pragma unroll
  for (int kt = 0; kt < 8; kt++)
#pragma unroll
    for (int nf = 0; nf < 2; nf++) {
      const int k = kt * 128 + wn * 32 + nf * 16 + ln;
      const bool mk = mask_s[k] != 0.f;
#pragma unroll
      for (int mf = 0; mf < 2; mf++)
#pragma unroll
        for (int r = 0; r < 4; r++)
          if (mk) rmax[mf][r] = fmaxf(rmax[mf][r], acc[kt][mf][nf][r]);
    }
#pragma unroll
  for (int off = 1; off < 16; off <<= 1)
#pragma unroll
    for (int mf = 0; mf < 2; mf++)
#pragma unroll
      for (int r = 0; r < 4; r++) rmax[mf][r] = fmaxf(rmax[mf][r], __shfl_xor(rmax[mf][r], off));
  if (ln == 0) {
#pragma unroll
    for (int mf = 0; mf < 2; mf++)
#pragma unroll
      for (int r = 0; r < 4; r++) red[wn][wm * 32 + mf * 16 + g * 4 + r] = rmax[mf][r];
  }
  __syncthreads();
#pragma unroll
  for (int mf = 0; mf < 2; mf++)
#pragma unroll
    for (int r = 0; r < 4; r++) {
      const int row = wm * 32 + mf * 16 + g * 4 + r;
      rmax[mf][r] = fmaxf(fmaxf(red[0][row], red[1][row]), fmaxf(red[2][row], red[3][row]));
    }
  __syncthreads();
  float rsum[2][4];
#pragma unroll
  for (int mf = 0; mf < 2; mf++)
#pragma unroll
    for (int r = 0; r < 4; r++) rsum[mf][r] = 0.f;
#pragma unroll
  for (int kt = 0; kt < 8; kt++)
#pragma unroll
    for (int nf = 0; nf < 2; nf++) {
      const int k = kt * 128 + wn * 32 + nf * 16 + ln;
      const bool mk = mask_s[k] != 0.f;
#pragma unroll
      for (int mf = 0; mf < 2; mf++)
#pragma unroll
        for (int r = 0; r < 4; r++)
          if (mk) rsum[mf][r] += __expf(acc[kt][mf][nf][r] - rmax[mf][r]);
    }
#pragma unroll
  for (int off = 1; off < 16; off <<= 1)
#pragma unroll
    for (int mf = 0; mf < 2; mf++)
#pragma unroll
      for (int r = 0; r < 4; r++) rsum[mf][r] += __shfl_xor(rsum[mf][r], off);
  if (ln == 0) {
#pragma unroll
    for (int mf = 0; mf < 2; mf++)
#pragma unroll
      for (int r = 0; r < 4; r++) red[wn][wm * 32 + mf * 16 + g * 4 + r] = rsum[mf][r];
  }
  __syncthreads();
  float rinv[2][4];
#pragma unroll
  for (int mf = 0; mf < 2; mf++)
#pragma unroll
    for (int r = 0; r < 4; r++) {
      const int row = wm * 32 + mf * 16 + g * 4 + r;
      rinv[mf][r] = 1.f / (red[0][row] + red[1][row] + red[2][row] + red[3][row]);
    }
  char* oc = (char*)dout;
#pragma unroll
  for (int kt = 0; kt < 8; kt++)
#pragma unroll
    for (int nf = 0; nf < 2; nf++) {
      const int k = kt * 128 + wn * 32 + nf * 16 + ln;
      const bool mk = mask_s[k] != 0.f;
#pragma unroll
      for (int mf = 0; mf < 2; mf++)
#pragma unroll
        for (int r = 0; r < 4; r++) {
          const int q = q0 + wm * 32 + mf * 16 + g * 4 + r;
          float p = mk ? __expf(acc[kt][mf][nf][r] - rmax[mf][r]) * rinv[mf][r] : 0.f;
          *(unsigned short*)(oc + (size_t)(b * 1024 + q) * 4096 + 2048 + k * 2) = f2bf(p);
        }
    }
}

__global__ __launch_bounds__(512, 2) void k_pv(const float* __restrict__ Key,
                                               float* __restrict__ dout, const int dh) {
  __shared__ __align__(16) short P[128 * 64];
  __shared__ __align__(16) short KT[512 * 64];
  const int t = threadIdx.x;
  const int qt = blockIdx.x, b = blockIdx.y;
  const int q0 = qt * 128, d0 = dh * 512;
  const int w = t >> 6, l = t & 63, wm = w >> 2, wd = w & 3, g = l >> 4, ln = l & 15;
  const f32x4 fz = {0.f, 0.f, 0.f, 0.f};
  f32x4 acc[4][8];
#pragma unroll
  for (int a = 0; a < 4; a++)
#pragma unroll
    for (int bq = 0; bq < 8; bq++) acc[a][bq] = fz;
  const char* ab = (const char*)dout;
  const int prow = t >> 2, pc0 = (t & 3) * 16;
#pragma unroll 1
  for (int k0 = 0; k0 < 1024; k0 += 64) {
    {
      const unsigned short* s =
          (const unsigned short*)(ab + (size_t)(b * 1024 + q0 + prow) * 4096 + 2048) + k0 + pc0;
      s16x8 p0 = *(const s16x8*)s, p1 = *(const s16x8*)(s + 8);
      *(s16x8*)&P[swz(prow, pc0)] = p0;
      *(s16x8*)&P[swz(prow, pc0 + 8)] = p1;
    }
    {
      const float* ksrc = Key + (size_t)b * 1024 * 1024 + (size_t)k0 * 1024 + d0 + t;
#pragma unroll
      for (int kg = 0; kg < 8; kg++) {
        s16x8 h;
#pragma unroll
        for (int jx = 0; jx < 8; jx++) h[jx] = (short)f2bf(ksrc[(size_t)(kg * 8 + jx) * 1024]);
        *(s16x8*)&KT[swz(t, kg * 8)] = h;
      }
    }
    __syncthreads();
#pragma unroll
    for (int ks = 0; ks < 2; ks++) {
      const int kc = ks * 32 + g * 8;
      s16x8 a[4], bb[8];
#pragma unroll
      for (int mf = 0; mf < 4; mf++) a[mf] = *(s16x8*)&P[swz(wm * 64 + mf * 16 + ln, kc)];
#pragma unroll
      for (int nf = 0; nf < 8; nf++) bb[nf] = *(s16x8*)&KT[swz(wd * 128 + nf * 16 + ln, kc)];
#pragma unroll
      for (int mf = 0; mf < 4; mf++)
#pragma unroll
        for (int nf = 0; nf < 8; nf++) acc[mf][nf] = MFMA16(a[mf], bb[nf], acc[mf][nf]);
    }
    __syncthreads();
  }
#pragma unroll
  for (int mf = 0; mf < 4; mf++)
#pragma unroll
    for (int nf = 0; nf < 8; nf++)
#pragma unroll
      for (int r = 0; r < 4; r++) {
        const int q = q0 + wm * 64 + mf * 16 + g * 4 + r;
        const int d = d0 + wd * 128 + nf * 16 + ln;
        dout[(size_t)(b * 1024 + q) * 1024 + d] = acc[mf][nf][r];
      }
}

extern "C" void kernel_launch(void* const* d_in, const int* in_sizes, int n_in,
                              void* d_out, int out_size, void* d_ws, size_t ws_size,
                              hipStream_t stream) {
  const float* Q = (const float*)d_in[0];
  const float* K = (const float*)d_in[1];
  const float* M = (const float*)d_in[2];
  const float* W = (const float*)d_in[3];
  const float* bias = (const float*)d_in[4];
  float* out = (float*)d_out;
  char* wsb = (char*)d_ws;
  (void)in_sizes; (void)n_in; (void)out_size;

  if (ws_size >= WS_TIER_A) {
    unsigned short* Khi = (unsigned short*)(wsb + OFF_KHI);
    unsigned short* Klo = (unsigned short*)(wsb + OFF_KLO);
    unsigned short* KhiT = (unsigned short*)(wsb + OFF_KHIT);
    unsigned short* Qhi = (unsigned short*)(wsb + OFF_QHI);
    unsigned short* Qlo = (unsigned short*)(wsb + OFF_QLO);
    unsigned short* Whi = (unsigned short*)(wsb + OFF_WHI);
    unsigned short* Wlo = (unsigned short*)(wsb + OFF_WLO);
    unsigned short* attnw = Qhi;  // Qhi/Qlo dead after k_qf2; reuse for attn
    k_cvt_k<<<dim3(16, 16, 32), 256, 0, stream>>>(K, Khi, Klo, KhiT);
    k_cvt_pair<<<16384, 256, 0, stream>>>(Q, Qhi, Qlo, 4194304);
    k_cvt_pair<<<512, 256, 0, stream>>>(W, Whi, Wlo, 131072);
    k_qf2<<<dim3(256, 8), 256, 0, stream>>>(Qhi, Qlo, Whi, Wlo, bias, out);
    k_attn2<<<dim3(16, 32), 512, 0, stream>>>(Khi, Klo, M, (const unsigned short*)out, attnw);
    k_pv2<<<dim3(8, 32, 2), 512, 0, stream>>>(KhiT, attnw, out);
  } else {
    k_qf<<<dim3(256, 8), 256, 0, stream>>>(Q, W, bias, out);
    k_attn<<<dim3(16, 32), 512, 0, stream>>>(K, M, out);
    k_pv<<<dim3(8, 32), 512, 0, stream>>>(K, out, 0);
    k_pv<<<dim3(8, 32), 512, 0, stream>>>(K, out, 1);
  }
}

// Round 7
// 722.346 us; speedup vs baseline: 1.2381x; 1.0075x over previous
//
#include <hip/hip_runtime.h>
#include <hip/hip_bf16.h>

// WordSentAtt: qf = relu(Q@W^T + b); S = qf@K^T (masked); attn = softmax; O = attn@K
// B=32, Lq=Lk=D=1024, f32 in/out. Split-bf16 (hi/lo) MFMA for qf and S.
// R7: (1) attn2 += s_setprio(1/0) around MFMA cluster (T5; structure is now
//     counted-vmcnt role-split where T5 measured +21-39%).
//     (2) pv2 -> T4 2-phase: dbuf P+KT = 160KiB LDS, vmcnt(0)+barrier once
//     per segment with stage issued after the barrier (m248 pattern).
//     (3) cvt_pair(Q) and cvt_pair(W) merged into one launch.

typedef __attribute__((ext_vector_type(4))) float f32x4;
typedef __attribute__((ext_vector_type(8))) short s16x8;

#define MFMA16(a, b, c) __builtin_amdgcn_mfma_f32_16x16x32_bf16((a), (b), (c), 0, 0, 0)

__device__ __forceinline__ unsigned short f2bf(float x) {
  unsigned u = __builtin_bit_cast(unsigned, x);
  return (unsigned short)((u + 0x7FFFu + ((u >> 16) & 1u)) >> 16);
}
__device__ __forceinline__ float bf2f(unsigned short h) {
  return __builtin_bit_cast(float, ((unsigned)h) << 16);
}
__device__ __forceinline__ int swz(int row, int col) {
  return (row * 64 + col) ^ ((row & 7) << 3);
}
__device__ __forceinline__ void cvt8(const float* __restrict__ s, s16x8& h8, s16x8& l8) {
  f32x4 a = *(const f32x4*)s;
  f32x4 b = *(const f32x4*)(s + 4);
#pragma unroll
  for (int i = 0; i < 8; i++) {
    float v = (i < 4) ? a[i] : b[i - 4];
    unsigned short hu = f2bf(v);
    unsigned short lu = f2bf(v - bf2f(hu));
    h8[i] = (short)hu;
    l8[i] = (short)lu;
  }
}
__device__ __forceinline__ void gld16(const void* g, void* lds) {
  __builtin_amdgcn_global_load_lds((const __attribute__((address_space(1))) unsigned int*)g,
                                   (__attribute__((address_space(3))) unsigned int*)lds, 16, 0, 0);
}

// ws layout (bytes)
#define OFF_KHI 0ULL
#define OFF_KLO 67108864ULL
#define OFF_KHIT 134217728ULL
#define OFF_QHI 201326592ULL  // qf2 inputs Qhi/Qlo; attn bf16 reuses QHI after qf2
#define OFF_QLO 268435456ULL
#define OFF_WHI 335544320ULL
#define OFF_WLO 337641472ULL
#define WS_TIER_A 339738624ULL
#define QA_LO 33554432ULL  // u16 offset of lo plane inside d_out frag layout

// ================= pre-convert kernels =================
// Q (4,194,304 x8-groups) and W (131,072 x8-groups) in ONE launch: 16896 blocks.
__global__ __launch_bounds__(256) void k_cvt_qw(const float* __restrict__ Q,
                                                unsigned short* __restrict__ Qhi,
                                                unsigned short* __restrict__ Qlo,
                                                const float* __restrict__ W,
                                                unsigned short* __restrict__ Whi,
                                                unsigned short* __restrict__ Wlo) {
  int i = blockIdx.x * 256 + threadIdx.x;
  s16x8 h, l;
  if (i < 4194304) {
    cvt8(Q + (size_t)i * 8, h, l);
    *(s16x8*)(Qhi + (size_t)i * 8) = h;
    *(s16x8*)(Qlo + (size_t)i * 8) = l;
  } else {
    int j = i - 4194304;
    if (j < 131072) {
      cvt8(W + (size_t)j * 8, h, l);
      *(s16x8*)(Whi + (size_t)j * 8) = h;
      *(s16x8*)(Wlo + (size_t)j * 8) = l;
    }
  }
}

__global__ __launch_bounds__(256) void k_cvt_k(const float* __restrict__ K,
                                               unsigned short* __restrict__ Khi,
                                               unsigned short* __restrict__ Klo,
                                               unsigned short* __restrict__ KhiT) {
  __shared__ unsigned T[64 * 65];
  const int t = threadIdx.x;
  const int db0 = blockIdx.x * 64, kb0 = blockIdx.y * 64, b = blockIdx.z;
  const size_t base = (size_t)b * 1024 * 1024;
#pragma unroll
  for (int i = 0; i < 2; i++) {
    const int r = (t >> 3) + i * 32, c0 = (t & 7) * 8;
    s16x8 h, l;
    cvt8(K + base + (size_t)(kb0 + r) * 1024 + db0 + c0, h, l);
    *(s16x8*)(Khi + base + (size_t)(kb0 + r) * 1024 + db0 + c0) = h;
    *(s16x8*)(Klo + base + (size_t)(kb0 + r) * 1024 + db0 + c0) = l;
#pragma unroll
    for (int j = 0; j < 8; j++)
      T[r * 65 + c0 + j] = ((unsigned)(unsigned short)h[j] << 16) | (unsigned short)l[j];
  }
  __syncthreads();
#pragma unroll
  for (int i = 0; i < 2; i++) {
    const int rd = (t >> 3) + i * 32, ck0 = (t & 7) * 8;
    s16x8 h;
#pragma unroll
    for (int j = 0; j < 8; j++) h[j] = (short)(unsigned short)(T[(ck0 + j) * 65 + rd] >> 16);
    *(s16x8*)(KhiT + base + (size_t)(db0 + rd) * 1024 + kb0 + ck0) = h;
  }
}

// ================= qf GEMM -> fragment-ordered output (unchanged) =============
__global__ __launch_bounds__(256, 2) void k_qf2(const unsigned short* __restrict__ Qhi,
                                                const unsigned short* __restrict__ Qlo,
                                                const unsigned short* __restrict__ Whi,
                                                const unsigned short* __restrict__ Wlo,
                                                const float* __restrict__ bias,
                                                float* __restrict__ outp) {
  __shared__ __align__(16) unsigned short Ah[128 * 64], Al[128 * 64], Bh[128 * 64], Bl[128 * 64];
  const int t = threadIdx.x;
  const int i = blockIdx.x + blockIdx.y * 256;
  const int x = i & 7, j = i >> 3;
  const int n0 = (j & 7) * 128;
  const int m0 = (x * 32 + (j >> 3)) * 128;
  const int w = t >> 6, l = t & 63, wm = w >> 1, wn = w & 1, g = l >> 4, ln = l & 15;
  const int lrow = l >> 3, lc8 = (l & 7) * 8;
  const f32x4 fz = {0.f, 0.f, 0.f, 0.f};
  f32x4 acc[4][4];
#pragma unroll
  for (int a = 0; a < 4; a++)
#pragma unroll
    for (int bq = 0; bq < 4; bq++) acc[a][bq] = fz;
#pragma unroll 1
  for (int k0 = 0; k0 < 1024; k0 += 64) {
#pragma unroll
    for (int jj = 0; jj < 4; jj++) {
      const int ch = w * 4 + jj;
      const int row = ch * 8 + lrow;
      const int sc = lc8 ^ (lrow << 3);
      gld16(Qhi + (size_t)(m0 + row) * 1024 + k0 + sc, &Ah[ch * 512]);
      gld16(Qlo + (size_t)(m0 + row) * 1024 + k0 + sc, &Al[ch * 512]);
      gld16(Whi + (size_t)(n0 + row) * 1024 + k0 + sc, &Bh[ch * 512]);
      gld16(Wlo + (size_t)(n0 + row) * 1024 + k0 + sc, &Bl[ch * 512]);
    }
    __syncthreads();
#pragma unroll
    for (int ks = 0; ks < 2; ks++) {
      const int kc = ks * 32 + g * 8;
      s16x8 ah[4], al[4], bh[4], bl[4];
#pragma unroll
      for (int mf = 0; mf < 4; mf++) {
        const int row = wm * 64 + mf * 16 + ln;
        const int idx = row * 64 + (kc ^ ((row & 7) << 3));
        ah[mf] = *(const s16x8*)&Ah[idx];
        al[mf] = *(const s16x8*)&Al[idx];
      }
#pragma unroll
      for (int nf = 0; nf < 4; nf++) {
        const int row = wn * 64 + nf * 16 + ln;
        const int idx = row * 64 + (kc ^ ((row & 7) << 3));
        bh[nf] = *(const s16x8*)&Bh[idx];
        bl[nf] = *(const s16x8*)&Bl[idx];
      }
#pragma unroll
      for (int mf = 0; mf < 4; mf++)
#pragma unroll
        for (int nf = 0; nf < 4; nf++) {
          acc[mf][nf] = MFMA16(ah[mf], bh[nf], acc[mf][nf]);
          acc[mf][nf] = MFMA16(ah[mf], bl[nf], acc[mf][nf]);
          acc[mf][nf] = MFMA16(al[mf], bh[nf], acc[mf][nf]);
        }
    }
    __syncthreads();
  }
  unsigned short* qA = (unsigned short*)outp;
#pragma unroll
  for (int nf = 0; nf < 4; nf++) {
    const int c = n0 + wn * 64 + nf * 16 + ln;
    const float bv = bias[c];
    const int kchunk = c >> 5, lhib = ((c >> 3) & 3) << 4, jj = c & 7;
#pragma unroll
    for (int mf = 0; mf < 4; mf++)
#pragma unroll
      for (int r = 0; r < 4; r++) {
        const int R = m0 + wm * 64 + mf * 16 + g * 4 + r;
        float v = acc[mf][nf][r] + bv;
        v = v > 0.f ? v : 0.f;
        unsigned short h = f2bf(v);
        const size_t fo = (((size_t)(R >> 4) * 32 + kchunk) * 64 + ((R & 15) + lhib)) * 8 + jj;
        qA[fo] = h;
        qA[QA_LO + fo] = f2bf(v - bf2f(h));
      }
  }
}

// ================= score GEMM + masked softmax (R6 T4 + R7 setprio) ==========
__global__ __launch_bounds__(512, 2) void k_attn2(const unsigned short* __restrict__ Khi,
                                                  const unsigned short* __restrict__ Klo,
                                                  const float* __restrict__ mask,
                                                  const unsigned short* __restrict__ qA,
                                                  unsigned short* __restrict__ attnw) {
  __shared__ __align__(16) unsigned short kbuf[2][2][128 * 64];
  __shared__ float mask_s[1024];
  __shared__ float red[4][64];
  const int t = threadIdx.x;
  const int i = blockIdx.y * 16 + blockIdx.x;
  const int x = i & 7, jj = i >> 3;
  const int b = x * 4 + (jj >> 4), qt = jj & 15;
  const int q0 = qt * 64;
  const int w = t >> 6, l = t & 63, wm = w >> 2, wn = w & 3, g = l >> 4, ln = l & 15;
  const int lrow = l >> 3, lc8 = (l & 7) * 8, sc = lc8 ^ (lrow << 3);
  for (int ii = t; ii < 1024; ii += 512) mask_s[ii] = mask[b * 1024 + ii];
  const f32x4 fz = {0.f, 0.f, 0.f, 0.f};
  f32x4 acc[8][2][2];
#pragma unroll
  for (int kt = 0; kt < 8; kt++)
#pragma unroll
    for (int mf = 0; mf < 2; mf++)
#pragma unroll
      for (int nf = 0; nf < 2; nf++) acc[kt][mf][nf] = fz;
  const size_t kbase = (size_t)b * 1024 * 1024;
  const int qblk0 = (b * 1024 + q0) >> 4;

  auto stageK = [&](int buf, int kt, int dc) {
#pragma unroll
    for (int jj2 = 0; jj2 < 2; jj2++) {
      const int ch = w * 2 + jj2;
      const int row = ch * 8 + lrow;
      const size_t go = kbase + (size_t)(kt * 128 + row) * 1024 + dc * 64 + sc;
      gld16(Khi + go, &kbuf[buf][0][ch * 512]);
      gld16(Klo + go, &kbuf[buf][1][ch * 512]);
    }
  };

  stageK(0, 0, 0);
  __syncthreads();
#pragma unroll 1
  for (int dc = 0; dc < 16; dc++) {
    s16x8 qh[2][2], ql[2][2];
#pragma unroll
    for (int mf = 0; mf < 2; mf++) {
      const int qb = qblk0 + wm * 2 + mf;
#pragma unroll
      for (int ks = 0; ks < 2; ks++) {
        const size_t fo = (((size_t)qb * 32 + dc * 2 + ks) * 64 + l) * 8;
        qh[mf][ks] = *(const s16x8*)(qA + fo);
        ql[mf][ks] = *(const s16x8*)(qA + QA_LO + fo);
      }
    }
#pragma unroll  // full: acc[kt] must be statically indexed (rule #20)
    for (int kt = 0; kt < 8; kt++) {
      const int snum = dc * 8 + kt;
      if (snum == 127) {
        asm volatile("s_waitcnt vmcnt(0)" ::: "memory");
      } else if (kt == 0) {
        asm volatile("s_waitcnt vmcnt(8)" ::: "memory");
      } else {
        asm volatile("s_waitcnt vmcnt(4)" ::: "memory");
      }
      __builtin_amdgcn_s_barrier();
      __builtin_amdgcn_sched_barrier(0);
      if (snum < 127) {
        const int nkt = (kt + 1) & 7;
        const int ndc = (kt == 7) ? dc + 1 : dc;
        stageK((snum + 1) & 1, nkt, ndc);
      }
      const int cur = snum & 1;
      __builtin_amdgcn_s_setprio(1);
#pragma unroll
      for (int ks = 0; ks < 2; ks++) {
        const int kc = ks * 32 + g * 8;
        s16x8 bh[2], bl[2];
#pragma unroll
        for (int nf = 0; nf < 2; nf++) {
          const int row = wn * 32 + nf * 16 + ln;
          const int idx = row * 64 + (kc ^ ((row & 7) << 3));
          bh[nf] = *(const s16x8*)&kbuf[cur][0][idx];
          bl[nf] = *(const s16x8*)&kbuf[cur][1][idx];
        }
#pragma unroll
        for (int mf = 0; mf < 2; mf++)
#pragma unroll
          for (int nf = 0; nf < 2; nf++) {
            acc[kt][mf][nf] = MFMA16(qh[mf][ks], bh[nf], acc[kt][mf][nf]);
            acc[kt][mf][nf] = MFMA16(qh[mf][ks], bl[nf], acc[kt][mf][nf]);
            acc[kt][mf][nf] = MFMA16(ql[mf][ks], bh[nf], acc[kt][mf][nf]);
          }
      }
      __builtin_amdgcn_s_setprio(0);
    }
  }
  __syncthreads();
  // ---- masked softmax ----
  float rmax[2][4];
#pragma unroll
  for (int mf = 0; mf < 2; mf++)
#pragma unroll
    for (int r = 0; r < 4; r++) rmax[mf][r] = -1e30f;
#pragma unroll
  for (int kt = 0; kt < 8; kt++)
#pragma unroll
    for (int nf = 0; nf < 2; nf++) {
      const int k = kt * 128 + wn * 32 + nf * 16 + ln;
      const bool mk = mask_s[k] != 0.f;
#pragma unroll
      for (int mf = 0; mf < 2; mf++)
#pragma unroll
        for (int r = 0; r < 4; r++)
          if (mk) rmax[mf][r] = fmaxf(rmax[mf][r], acc[kt][mf][nf][r]);
    }
#pragma unroll
  for (int off = 1; off < 16; off <<= 1)
#pragma unroll
    for (int mf = 0; mf < 2; mf++)
#pragma unroll
      for (int r = 0; r < 4; r++) rmax[mf][r] = fmaxf(rmax[mf][r], __shfl_xor(rmax[mf][r], off));
  if (ln == 0) {
#pragma unroll
    for (int mf = 0; mf < 2; mf++)
#pragma unroll
      for (int r = 0; r < 4; r++) red[wn][wm * 32 + mf * 16 + g * 4 + r] = rmax[mf][r];
  }
  __syncthreads();
#pragma unroll
  for (int mf = 0; mf < 2; mf++)
#pragma unroll
    for (int r = 0; r < 4; r++) {
      const int row = wm * 32 + mf * 16 + g * 4 + r;
      rmax[mf][r] = fmaxf(fmaxf(red[0][row], red[1][row]), fmaxf(red[2][row], red[3][row]));
    }
  __syncthreads();
  float rsum[2][4];
#pragma unroll
  for (int mf = 0; mf < 2; mf++)
#pragma unroll
    for (int r = 0; r < 4; r++) rsum[mf][r] = 0.f;
#pragma unroll
  for (int kt = 0; kt < 8; kt++)
#pragma unroll
    for (int nf = 0; nf < 2; nf++) {
      const int k = kt * 128 + wn * 32 + nf * 16 + ln;
      const bool mk = mask_s[k] != 0.f;
#pragma unroll
      for (int mf = 0; mf < 2; mf++)
#pragma unroll
        for (int r = 0; r < 4; r++)
          if (mk) rsum[mf][r] += __expf(acc[kt][mf][nf][r] - rmax[mf][r]);
    }
#pragma unroll
  for (int off = 1; off < 16; off <<= 1)
#pragma unroll
    for (int mf = 0; mf < 2; mf++)
#pragma unroll
      for (int r = 0; r < 4; r++) rsum[mf][r] += __shfl_xor(rsum[mf][r], off);
  if (ln == 0) {
#pragma unroll
    for (int mf = 0; mf < 2; mf++)
#pragma unroll
      for (int r = 0; r < 4; r++) red[wn][wm * 32 + mf * 16 + g * 4 + r] = rsum[mf][r];
  }
  __syncthreads();
  float rinv[2][4];
#pragma unroll
  for (int mf = 0; mf < 2; mf++)
#pragma unroll
    for (int r = 0; r < 4; r++) {
      const int row = wm * 32 + mf * 16 + g * 4 + r;
      rinv[mf][r] = 1.f / (red[0][row] + red[1][row] + red[2][row] + red[3][row]);
    }
#pragma unroll
  for (int kt = 0; kt < 8; kt++)
#pragma unroll
    for (int nf = 0; nf < 2; nf++) {
      const int k = kt * 128 + wn * 32 + nf * 16 + ln;
      const bool mk = mask_s[k] != 0.f;
#pragma unroll
      for (int mf = 0; mf < 2; mf++)
#pragma unroll
        for (int r = 0; r < 4; r++) {
          const int q = q0 + wm * 32 + mf * 16 + g * 4 + r;
          float p = mk ? __expf(acc[kt][mf][nf][r] - rmax[mf][r]) * rinv[mf][r] : 0.f;
          attnw[(size_t)(b * 1024 + q) * 1024 + k] = f2bf(p);
        }
    }
}

// ================= O = attn @ K via KhiT (R7: T4 2-phase, dbuf 160KiB) ========
__global__ __launch_bounds__(512, 1) void k_pv2(const unsigned short* __restrict__ KhiT,
                                                const unsigned short* __restrict__ attnw,
                                                float* __restrict__ dout) {
  __shared__ __align__(16) unsigned short Pb[2][128 * 64];   // 2 x 16 KiB
  __shared__ __align__(16) unsigned short KTb[2][512 * 64];  // 2 x 64 KiB
  const int t = threadIdx.x;
  const int i = blockIdx.y * 8 + blockIdx.x;
  const int x = i & 7, jj = i >> 3;
  const int b = x * 4 + (jj >> 3), qt = jj & 7;
  const int q0 = qt * 128, d0 = blockIdx.z * 512;
  const int w = t >> 6, l = t & 63, wm = w >> 2, wd = w & 3, g = l >> 4, ln = l & 15;
  const int lrow = l >> 3, lc8 = (l & 7) * 8, sc = lc8 ^ (lrow << 3);
  const f32x4 fz = {0.f, 0.f, 0.f, 0.f};
  f32x4 acc[4][8];
#pragma unroll
  for (int a = 0; a < 4; a++)
#pragma unroll
    for (int bq = 0; bq < 8; bq++) acc[a][bq] = fz;
  const size_t kbase = (size_t)b * 1024 * 1024;

  auto stageP = [&](int buf, int k0) {
#pragma unroll
    for (int jj2 = 0; jj2 < 2; jj2++) {
      const int ch = w * 2 + jj2;
      const int row = ch * 8 + lrow;
      gld16(attnw + (size_t)(b * 1024 + q0 + row) * 1024 + k0 + sc, &Pb[buf][ch * 512]);
    }
  };
  auto stageKT = [&](int buf, int k0) {
#pragma unroll
    for (int jj2 = 0; jj2 < 8; jj2++) {
      const int ch = w * 8 + jj2;
      const int row = ch * 8 + lrow;
      gld16(KhiT + kbase + (size_t)(d0 + row) * 1024 + k0 + sc, &KTb[buf][ch * 512]);
    }
  };

  stageP(0, 0);
  stageKT(0, 0);
#pragma unroll 1
  for (int s = 0; s < 16; s++) {
    asm volatile("s_waitcnt vmcnt(0)" ::: "memory");  // stage(s) done (issued 1 seg ago)
    __builtin_amdgcn_s_barrier();
    __builtin_amdgcn_sched_barrier(0);
    if (s < 15) {
      stageP((s + 1) & 1, (s + 1) * 64);
      stageKT((s + 1) & 1, (s + 1) * 64);
    }
    const int cur = s & 1;
    __builtin_amdgcn_s_setprio(1);
#pragma unroll
    for (int ks = 0; ks < 2; ks++) {
      const int kc = ks * 32 + g * 8;
      s16x8 a[4], bb[8];
#pragma unroll
      for (int mf = 0; mf < 4; mf++) {
        const int row = wm * 64 + mf * 16 + ln;
        a[mf] = *(const s16x8*)&Pb[cur][row * 64 + (kc ^ ((row & 7) << 3))];
      }
#pragma unroll
      for (int nf = 0; nf < 8; nf++) {
        const int row = wd * 128 + nf * 16 + ln;
        bb[nf] = *(const s16x8*)&KTb[cur][row * 64 + (kc ^ ((row & 7) << 3))];
      }
#pragma unroll
      for (int mf = 0; mf < 4; mf++)
#pragma unroll
        for (int nf = 0; nf < 8; nf++) acc[mf][nf] = MFMA16(a[mf], bb[nf], acc[mf][nf]);
    }
    __builtin_amdgcn_s_setprio(0);
  }
#pragma unroll
  for (int mf = 0; mf < 4; mf++)
#pragma unroll
    for (int nf = 0; nf < 8; nf++)
#pragma unroll
      for (int r = 0; r < 4; r++) {
        const int q = q0 + wm * 64 + mf * 16 + g * 4 + r;
        const int d = d0 + wd * 128 + nf * 16 + ln;
        dout[(size_t)(b * 1024 + q) * 1024 + d] = acc[mf][nf][r];
      }
}

// ================= Tier C: round-1 kernels (fallback, unchanged) =============
__global__ __launch_bounds__(256, 2) void k_qf(const float* __restrict__ Q,
                                               const float* __restrict__ W,
                                               const float* __restrict__ bias,
                                               float* __restrict__ qf) {
  __shared__ __align__(16) short Ah[128 * 64], Al[128 * 64], Bh[128 * 64], Bl[128 * 64];
  const int t = threadIdx.x;
  const int m0 = blockIdx.x * 128, n0 = blockIdx.y * 128;
  const int w = t >> 6, l = t & 63, wm = w >> 1, wn = w & 1, g = l >> 4, ln = l & 15;
  const f32x4 fz = {0.f, 0.f, 0.f, 0.f};
  f32x4 acc[4][4];
#pragma unroll
  for (int a = 0; a < 4; a++)
#pragma unroll
    for (int bq = 0; bq < 4; bq++) acc[a][bq] = fz;
  const int srow = t >> 1, scol = (t & 1) * 32;
#pragma unroll 1
  for (int k0 = 0; k0 < 1024; k0 += 64) {
    const float* sa = Q + (size_t)(m0 + srow) * 1024 + k0 + scol;
    const float* sb = W + (size_t)(n0 + srow) * 1024 + k0 + scol;
#pragma unroll
    for (int c = 0; c < 32; c += 8) {
      s16x8 h, lo;
      cvt8(sa + c, h, lo);
      int si = swz(srow, scol + c);
      *(s16x8*)&Ah[si] = h;
      *(s16x8*)&Al[si] = lo;
    }
#pragma unroll
    for (int c = 0; c < 32; c += 8) {
      s16x8 h, lo;
      cvt8(sb + c, h, lo);
      int si = swz(srow, scol + c);
      *(s16x8*)&Bh[si] = h;
      *(s16x8*)&Bl[si] = lo;
    }
    __syncthreads();
#pragma unroll
    for (int ks = 0; ks < 2; ks++) {
      const int kc = ks * 32 + g * 8;
      s16x8 ah[4], al[4], bh[4], bl[4];
#pragma unroll
      for (int mf = 0; mf < 4; mf++) {
        int si = swz(wm * 64 + mf * 16 + ln, kc);
        ah[mf] = *(s16x8*)&Ah[si];
        al[mf] = *(s16x8*)&Al[si];
      }
#pragma unroll
      for (int nf = 0; nf < 4; nf++) {
        int si = swz(wn * 64 + nf * 16 + ln, kc);
        bh[nf] = *(s16x8*)&Bh[si];
        bl[nf] = *(s16x8*)&Bl[si];
      }
#pragma unroll
      for (int mf = 0; mf < 4; mf++)
#pragma unroll
        for (int nf = 0; nf < 4; nf++) {
          acc[mf][nf] = MFMA16(ah[mf], bh[nf], acc[mf][nf]);
          acc[mf][nf] = MFMA16(ah[mf], bl[nf], acc[mf][nf]);
          acc[mf][nf] = MFMA16(al[mf], bh[nf], acc[mf][nf]);
        }
    }
    __syncthreads();
  }
#pragma unroll
  for (int nf = 0; nf < 4; nf++) {
    const int col = n0 + wn * 64 + nf * 16 + ln;
    const float bv = bias[col];
#pragma unroll
    for (int mf = 0; mf < 4; mf++)
#pragma unroll
      for (int r = 0; r < 4; r++) {
        const int row = m0 + wm * 64 + mf * 16 + g * 4 + r;
        float v = acc[mf][nf][r] + bv;
        qf[(size_t)row * 1024 + col] = v > 0.f ? v : 0.f;
      }
  }
}

__global__ __launch_bounds__(512, 2) void k_attn(const float* __restrict__ Key,
                                                 const float* __restrict__ mask,
                                                 float* __restrict__ dout) {
  __shared__ __align__(16) short qh[64 * 64], qlo[64 * 64], kh[128 * 64], klo[128 * 64];
  __shared__ float mask_s[1024];
  __shared__ float red[4][64];
  const int t = threadIdx.x;
  const int qt = blockIdx.x, b = blockIdx.y;
  const int q0 = qt * 64;
  const int w = t >> 6, l = t & 63, wm = w >> 2, wn = w & 3, g = l >> 4, ln = l & 15;
  for (int i = t; i < 1024; i += 512) mask_s[i] = mask[b * 1024 + i];
  const f32x4 fz = {0.f, 0.f, 0.f, 0.f};
  f32x4 acc[8][2][2];
#pragma unroll
  for (int kt = 0; kt < 8; kt++)
#pragma unroll
    for (int mf = 0; mf < 2; mf++)
#pragma unroll
      for (int nf = 0; nf < 2; nf++) acc[kt][mf][nf] = fz;
  const float* qfb = dout + (size_t)(b * 1024 + q0) * 1024;
  const float* kb = Key + (size_t)b * 1024 * 1024;
  const int qrow = t >> 3, qcol = (t & 7) * 8;
  const int krow = t >> 2, kcol0 = (t & 3) * 16;
#pragma unroll 1
  for (int dc = 0; dc < 16; dc++) {
    {
      s16x8 h, lo;
      cvt8(qfb + (size_t)qrow * 1024 + dc * 64 + qcol, h, lo);
      int si = swz(qrow, qcol);
      *(s16x8*)&qh[si] = h;
      *(s16x8*)&qlo[si] = lo;
    }
#pragma unroll
    for (int kt = 0; kt < 8; kt++) {
      {
        const float* s = kb + (size_t)(kt * 128 + krow) * 1024 + dc * 64 + kcol0;
        s16x8 h, lo;
        cvt8(s, h, lo);
        int si = swz(krow, kcol0);
        *(s16x8*)&kh[si] = h;
        *(s16x8*)&klo[si] = lo;
        cvt8(s + 8, h, lo);
        si = swz(krow, kcol0 + 8);
        *(s16x8*)&kh[si] = h;
        *(s16x8*)&klo[si] = lo;
      }
      __syncthreads();
#pragma unroll
      for (int ks = 0; ks < 2; ks++) {
        const int kc = ks * 32 + g * 8;
        s16x8 ah[2], al2[2], bh[2], bl[2];
#pragma unroll
        for (int mf = 0; mf < 2; mf++) {
          int si = swz(wm * 32 + mf * 16 + ln, kc);
          ah[mf] = *(s16x8*)&qh[si];
          al2[mf] = *(s16x8*)&qlo[si];
        }
#pragma unroll
        for (int nf = 0; nf < 2; nf++) {
          int si = swz(wn * 32 + nf * 16 + ln, kc);
          bh[nf] = *(s16x8*)&kh[si];
          bl[nf] = *(s16x8*)&klo[si];
        }
#pragma unroll
        for (int mf = 0; mf < 2; mf++)
#pragma unroll
          for (int nf = 0; nf < 2; nf++) {
            acc[kt][mf][nf] = MFMA16(ah[mf], bh[nf], acc[kt][mf][nf]);
            acc[kt][mf][nf] = MFMA16(ah[mf], bl[nf], acc[kt][mf][nf]);
            acc[kt][mf][nf] = MFMA16(al2[mf], bh[nf], acc[kt][mf][nf]);
          }
      }
      __syncthreads();
    }
  }
  float rmax[2][4];
#pragma unroll
  for (int mf = 0; mf < 2; mf++)
#pragma unroll
    for (int r = 0; r < 4; r++) rmax[mf][r] = -1e30f;
#pragma unroll
  for (int kt = 0; kt < 8; kt++)
#pragma unroll
    for (int nf = 0; nf < 2; nf++) {
      const int k = kt * 128 + wn * 32 + nf * 16 + ln;
      const bool mk = mask_s[k] != 0.f;
#pragma unroll
      for (int mf = 0; mf < 2; mf++)
#pragma unroll
        for (int r = 0; r < 4; r++)
          if (mk) rmax[mf][r] = fmaxf(rmax[mf][r], acc[kt][mf][nf][r]);
    }
#pragma unroll
  for (int off = 1; off < 16; off <<= 1)
#pragma unroll
    for (int mf = 0; mf < 2; mf++)
#pragma unroll
      for (int r = 0; r < 4; r++) rmax[mf][r] = fmaxf(rmax[mf][r], __shfl_xor(rmax[mf][r], off));
  if (ln == 0) {
#pragma unroll
    for (int mf = 0; mf < 2; mf++)
#pragma unroll
      for (int r = 0; r < 4; r++) red[wn][wm * 32 + mf * 16 + g * 4 + r] = rmax[mf][r];
  }
  __syncthreads();
#pragma unroll
  for (int mf = 0; mf < 2; mf++)
#pragma unroll
    for (int r = 0; r < 4; r++) {
      const int row = wm * 32 + mf * 16 + g * 4 + r;
      rmax[mf][r] = fmaxf(fmaxf(red[0][row], red[1][row]), fmaxf(red[2][row], red[3][row]));
    }
  __syncthreads();
  float rsum[2][4];
#pragma unroll
  for (int mf = 0; mf < 2; mf++)
#pragma unroll
    for (int r = 0; r < 4; r++) rsum[mf][r] = 0.f;
#pragma unroll
  for (int kt = 0; kt < 8; kt++)
#pragma unroll
    for (int nf = 0; nf < 2; nf++) {
      const int k = kt * 128 + wn * 32 + nf * 16 + ln;
      const bool mk = mask_s[k] != 0.f;
#pragma unroll
      for (int mf = 0; mf < 2; mf++)
#pragma unroll
        for (int r = 0; r < 4; r++)
          if (mk) rsum[mf][r] += __expf(acc[kt][mf][nf][r] - rmax[mf][r]);
    }
#pragma unroll
  for (int off = 1; off < 16; off <<= 1)
#pragma unroll
    for (int mf = 0; mf < 2; mf++)
#pragma unroll
      for (int r = 0; r < 4; r++) rsum[mf][r] += __shfl_xor(rsum[mf][r], off);
  if (ln == 0) {
#pragma unroll
    for (int mf = 0; mf < 2; mf++)
#pragma unroll
      for (int r = 0; r < 4; r++) red[wn][wm * 32 + mf * 16 + g * 4 + r] = rsum[mf][r];
  }
  __syncthreads();
  float rinv[2][4];
#pragma unroll
  for (int mf = 0; mf < 2; mf++)
#pragma unroll
    for (int r = 0; r < 4; r++) {
      const int row = wm * 32 + mf * 16 + g * 4 + r;
      rinv[mf][r] = 1.f / (red[0][row] + red[1][row] + red[2][row] + red[3][row]);
    }
  char* oc = (char*)dout;
#pragma unroll
  for (int kt = 0; kt < 8; kt++)
#pragma unroll
    for (int nf = 0; nf < 2; nf++) {
      const int k = kt * 128 + wn * 32 + nf * 16 + ln;
      const bool mk = mask_s[k] != 0.f;
#pragma unroll
      for (int mf = 0; mf < 2; mf++)
#pragma unroll
        for (int r = 0; r < 4; r++) {
          const int q = q0 + wm * 32 + mf * 16 + g * 4 + r;
          float p = mk ? __expf(acc[kt][mf][nf][r] - rmax[mf][r]) * rinv[mf][r] : 0.f;
          *(unsigned short*)(oc + (size_t)(b * 1024 + q) * 4096 + 2048 + k * 2) = f2bf(p);
        }
    }
}

__global__ __launch_bounds__(512, 2) void k_pv(const float* __restrict__ Key,
                                               float* __restrict__ dout, const int dh) {
  __shared__ __align__(16) short P[128 * 64];
  __shared__ __align__(16) short KT[512 * 64];
  const int t = threadIdx.x;
  const int qt = blockIdx.x, b = blockIdx.y;
  const int q0 = qt * 128, d0 = dh * 512;
  const int w = t >> 6, l = t & 63, wm = w >> 2, wd = w & 3, g = l >> 4, ln = l & 15;
  const f32x4 fz = {0.f, 0.f, 0.f, 0.f};
  f32x4 acc[4][8];
#pragma unroll
  for (int a = 0; a < 4; a++)
#pragma unroll
    for (int bq = 0; bq < 8; bq++) acc[a][bq] = fz;
  const char* ab = (const char*)dout;
  const int prow = t >> 2, pc0 = (t & 3) * 16;
#pragma unroll 1
  for (int k0 = 0; k0 < 1024; k0 += 64) {
    {
      const unsigned short* s =
          (const unsigned short*)(ab + (size_t)(b * 1024 + q0 + prow) * 4096 + 2048) + k0 + pc0;
      s16x8 p0 = *(const s16x8*)s, p1 = *(const s16x8*)(s + 8);
      *(s16x8*)&P[swz(prow, pc0)] = p0;
      *(s16x8*)&P[swz(prow, pc0 + 8)] = p1;
    }
    {
      const float* ksrc = Key + (size_t)b * 1024 * 1024 + (size_t)k0 * 1024 + d0 + t;
#pragma unroll
      for (int kg = 0; kg < 8; kg++) {
        s16x8 h;
#pragma unroll
        for (int jx = 0; jx < 8; jx++) h[jx] = (short)f2bf(ksrc[(size_t)(kg * 8 + jx) * 1024]);
        *(s16x8*)&KT[swz(t, kg * 8)] = h;
      }
    }
    __syncthreads();
#pragma unroll
    for (int ks = 0; ks < 2; ks++) {
      const int kc = ks * 32 + g * 8;
      s16x8 a[4], bb[8];
#pragma unroll
      for (int mf = 0; mf < 4; mf++) a[mf] = *(s16x8*)&P[swz(wm * 64 + mf * 16 + ln, kc)];
#pragma unroll
      for (int nf = 0; nf < 8; nf++) bb[nf] = *(s16x8*)&KT[swz(wd * 128 + nf * 16 + ln, kc)];
#pragma unroll
      for (int mf = 0; mf < 4; mf++)
#pragma unroll
        for (int nf = 0; nf < 8; nf++) acc[mf][nf] = MFMA16(a[mf], bb[nf], acc[mf][nf]);
    }
    __syncthreads();
  }
#pragma unroll
  for (int mf = 0; mf < 4; mf++)
#pragma unroll
    for (int nf = 0; nf < 8; nf++)
#pragma unroll
      for (int r = 0; r < 4; r++) {
        const int q = q0 + wm * 64 + mf * 16 + g * 4 + r;
        const int d = d0 + wd * 128 + nf * 16 + ln;
        dout[(size_t)(b * 1024 + q) * 1024 + d] = acc[mf][nf][r];
      }
}

extern "C" void kernel_launch(void* const* d_in, const int* in_sizes, int n_in,
                              void* d_out, int out_size, void* d_ws, size_t ws_size,
                              hipStream_t stream) {
  const float* Q = (const float*)d_in[0];
  const float* K = (const float*)d_in[1];
  const float* M = (const float*)d_in[2];
  const float* W = (const float*)d_in[3];
  const float* bias = (const float*)d_in[4];
  float* out = (float*)d_out;
  char* wsb = (char*)d_ws;
  (void)in_sizes; (void)n_in; (void)out_size;

  if (ws_size >= WS_TIER_A) {
    unsigned short* Khi = (unsigned short*)(wsb + OFF_KHI);
    unsigned short* Klo = (unsigned short*)(wsb + OFF_KLO);
    unsigned short* KhiT = (unsigned short*)(wsb + OFF_KHIT);
    unsigned short* Qhi = (unsigned short*)(wsb + OFF_QHI);
    unsigned short* Qlo = (unsigned short*)(wsb + OFF_QLO);
    unsigned short* Whi = (unsigned short*)(wsb + OFF_WHI);
    unsigned short* Wlo = (unsigned short*)(wsb + OFF_WLO);
    unsigned short* attnw = Qhi;  // Qhi/Qlo dead after k_qf2; reuse for attn
    k_cvt_k<<<dim3(16, 16, 32), 256, 0, stream>>>(K, Khi, Klo, KhiT);
    k_cvt_qw<<<16896, 256, 0, stream>>>(Q, Qhi, Qlo, W, Whi, Wlo);
    k_qf2<<<dim3(256, 8), 256, 0, stream>>>(Qhi, Qlo, Whi, Wlo, bias, out);
    k_attn2<<<dim3(16, 32), 512, 0, stream>>>(Khi, Klo, M, (const unsigned short*)out, attnw);
    k_pv2<<<dim3(8, 32, 2), 512, 0, stream>>>(KhiT, attnw, out);
  } else {
    k_qf<<<dim3(256, 8), 256, 0, stream>>>(Q, W, bias, out);
    k_attn<<<dim3(16, 32), 512, 0, stream>>>(K, M, out);
    k_pv<<<dim3(8, 32), 512, 0, stream>>>(K, out, 0);
    k_pv<<<dim3(8, 32), 512, 0, stream>>>(K, out, 1);
  }
}